// Round 1
// baseline (902.684 us; speedup 1.0000x reference)
//
#include <hip/hip_runtime.h>
#include <cstdint>
#include <cstddef>

#define NN 50000
#define NE 800000
#define NG 64

// ---------------- Linear: Y[n,64] = X[n,IN] @ W[IN,64] ----------------
template<int IN>
__global__ __launch_bounds__(256) void linear_kernel(
    const float* __restrict__ X, const float* __restrict__ W,
    float* __restrict__ Y, int n_nodes) {
  constexpr int OUT = 64;
  constexpr int NPB = 32;  // nodes per block
  __shared__ float xs[NPB][IN];
  __shared__ float ws[IN][OUT];
  const int tid = threadIdx.x;
  const int node0 = blockIdx.x * NPB;

  // stage W (coalesced float4)
  for (int i = tid; i < IN * OUT / 4; i += 256)
    ((float4*)ws)[i] = ((const float4*)W)[i];
  // stage X rows (contiguous; zero-fill OOB tail)
  const size_t gbase = (size_t)node0 * IN;
  const size_t gmax  = (size_t)n_nodes * IN;
  for (int i = tid; i < NPB * IN / 4; i += 256) {
    size_t g = gbase + (size_t)i * 4;
    float4 v = make_float4(0.f, 0.f, 0.f, 0.f);
    if (g + 3 < gmax) v = ((const float4*)X)[g / 4];
    ((float4*)xs)[i] = v;
  }
  __syncthreads();

  const int c  = tid & 63;   // output channel (lane)
  const int rg = tid >> 6;   // wave id -> row group
  float acc[8];
  #pragma unroll
  for (int j = 0; j < 8; ++j) acc[j] = 0.f;

  for (int k = 0; k < IN; k += 4) {
    // 2 lanes/bank, distinct addresses -> conflict-free
    float w0 = ws[k][c], w1 = ws[k+1][c], w2 = ws[k+2][c], w3 = ws[k+3][c];
    #pragma unroll
    for (int j = 0; j < 8; ++j) {
      // same address across the wave -> LDS broadcast
      float4 xv = *(const float4*)&xs[rg*8 + j][k];
      acc[j] = fmaf(xv.x, w0, acc[j]);
      acc[j] = fmaf(xv.y, w1, acc[j]);
      acc[j] = fmaf(xv.z, w2, acc[j]);
      acc[j] = fmaf(xv.w, w3, acc[j]);
    }
  }
  #pragma unroll
  for (int j = 0; j < 8; ++j) {
    int node = node0 + rg*8 + j;
    if (node < n_nodes) Y[(size_t)node * 64 + c] = acc[j];
  }
}

// ---------------- Edge scatter-add: out[dst] += H[src], one wave per edge ----------------
__global__ __launch_bounds__(256) void scatter_kernel(
    const float* __restrict__ H, const int* __restrict__ ei,
    float* __restrict__ out, int n_edges) {
  int wid = (int)((blockIdx.x * 256u + (unsigned)threadIdx.x) >> 6);
  int c = threadIdx.x & 63;
  if (wid >= n_edges) return;
  int s = ei[wid];            // src (broadcast load)
  int d = ei[NE + wid];       // dst
  atomicAdd(&out[(size_t)d * 64 + c], H[(size_t)s * 64 + c]);
}

// ---------------- bias + relu, in place ----------------
__global__ __launch_bounds__(256) void bias_relu_kernel(
    float* __restrict__ h, const float* __restrict__ b, size_t n) {
  size_t i = (size_t)blockIdx.x * 256 + threadIdx.x;
  if (i < n) {
    float v = h[i] + b[i & 63];
    h[i] = v > 0.f ? v : 0.f;
  }
}

// ---------------- mean-pool accumulation (atomics; batch sorted) ----------------
__global__ __launch_bounds__(256) void pool_kernel(
    const float* __restrict__ h, const int* __restrict__ batch,
    float* __restrict__ sums, int* __restrict__ counts, int n_nodes) {
  int node = (int)((blockIdx.x * 256u + (unsigned)threadIdx.x) >> 6);
  int c = threadIdx.x & 63;
  if (node >= n_nodes) return;
  int g = batch[node];
  atomicAdd(&sums[g * 64 + c], h[(size_t)node * 64 + c]);
  if (c == 0) atomicAdd(&counts[g], 1);
}

// ---------------- head: pooled -> fc1(relu) -> fc2 -> log_softmax ----------------
__global__ __launch_bounds__(64) void head_kernel(
    const float* __restrict__ sums, const int* __restrict__ counts,
    const float* __restrict__ fc1w, const float* __restrict__ fc1b,
    const float* __restrict__ fc2w, const float* __restrict__ fc2b,
    float* __restrict__ out) {
  int g = blockIdx.x;
  int t = threadIdx.x;
  __shared__ float pooled[64];
  __shared__ float z1[32];
  __shared__ float z2[10];
  float cnt = (float)counts[g];
  cnt = cnt > 1.f ? cnt : 1.f;
  pooled[t] = sums[g * 64 + t] / cnt;
  __syncthreads();
  if (t < 32) {
    float a = fc1b[t];
    for (int k = 0; k < 64; ++k) a = fmaf(pooled[k], fc1w[k * 32 + t], a);
    z1[t] = a > 0.f ? a : 0.f;
  }
  __syncthreads();
  if (t < 10) {
    float a = fc2b[t];
    for (int k = 0; k < 32; ++k) a = fmaf(z1[k], fc2w[k * 10 + t], a);
    z2[t] = a;
  }
  __syncthreads();
  if (t == 0) {
    float m = z2[0];
    for (int i = 1; i < 10; ++i) m = fmaxf(m, z2[i]);
    float s = 0.f;
    for (int i = 0; i < 10; ++i) s += expf(z2[i] - m);
    float lse = logf(s) + m;
    for (int i = 0; i < 10; ++i) out[g * 10 + i] = z2[i] - lse;
  }
}

extern "C" void kernel_launch(void* const* d_in, const int* in_sizes, int n_in,
                              void* d_out, int out_size, void* d_ws, size_t ws_size,
                              hipStream_t stream) {
  const float* x    = (const float*)d_in[0];
  const int*   ei   = (const int*)  d_in[1];   // [2, NE] (src row, then dst row)
  const int*   bat  = (const int*)  d_in[2];
  const float* W1   = (const float*)d_in[3];
  const float* b1   = (const float*)d_in[4];
  const float* W2   = (const float*)d_in[5];
  const float* b2   = (const float*)d_in[6];
  const float* fc1w = (const float*)d_in[7];
  const float* fc1b = (const float*)d_in[8];
  const float* fc2w = (const float*)d_in[9];
  const float* fc2b = (const float*)d_in[10];
  float* out = (float*)d_out;

  char* ws = (char*)d_ws;
  float* A     = (float*)ws;                        // [NN,64] 12.8 MB
  float* B     = (float*)(ws + 12800000);           // [NN,64] 12.8 MB
  float* sums  = (float*)(ws + 25600000);           // [NG,64] 16 KB
  int*   cnts  = (int*)  (ws + 25616384);           // [NG]

  const size_t HFEAT = (size_t)NN * 64;

  // ---- layer 1 ----
  linear_kernel<128><<<(NN + 31) / 32, 256, 0, stream>>>(x, W1, A, NN);
  hipMemsetAsync(B, 0, HFEAT * sizeof(float), stream);
  scatter_kernel<<<(NE * 64) / 256, 256, 0, stream>>>(A, ei, B, NE);
  bias_relu_kernel<<<(int)(HFEAT / 256), 256, 0, stream>>>(B, b1, HFEAT);

  // ---- layer 2 ----
  linear_kernel<64><<<(NN + 31) / 32, 256, 0, stream>>>(B, W2, A, NN);
  hipMemsetAsync(B, 0, HFEAT * sizeof(float), stream);
  scatter_kernel<<<(NE * 64) / 256, 256, 0, stream>>>(A, ei, B, NE);
  bias_relu_kernel<<<(int)(HFEAT / 256), 256, 0, stream>>>(B, b2, HFEAT);

  // ---- pool ----
  hipMemsetAsync(sums, 0, NG * 64 * sizeof(float) + NG * sizeof(int), stream);
  pool_kernel<<<(NN * 64) / 256, 256, 0, stream>>>(B, bat, sums, cnts, NN);

  // ---- head ----
  head_kernel<<<NG, 64, 0, stream>>>(sums, cnts, fc1w, fc1b, fc2w, fc2b, out);
}

// Round 2
// 592.215 us; speedup vs baseline: 1.5243x; 1.5243x over previous
//
#include <hip/hip_runtime.h>
#include <cstdint>
#include <cstddef>

#define NN 50000
#define NE 800000
#define NG 64

// ---------------- Linear: Y[n,64] = relu?(X + preb) @ W ----------------
// PREB: apply per-channel bias + ReLU to X while staging (fused prev layer epilogue)
template<int IN, bool PREB>
__global__ __launch_bounds__(256) void linear_kernel(
    const float* __restrict__ X, const float* __restrict__ preb,
    const float* __restrict__ W, float* __restrict__ Y, int n_nodes) {
  constexpr int OUT = 64;
  constexpr int NPB = 32;  // nodes per block
  __shared__ float xs[NPB][IN];
  __shared__ float ws[IN][OUT];
  const int tid = threadIdx.x;
  const int node0 = blockIdx.x * NPB;

  // stage W (coalesced float4)
  for (int i = tid; i < IN * OUT / 4; i += 256)
    ((float4*)ws)[i] = ((const float4*)W)[i];
  // stage X rows (contiguous; zero-fill OOB tail), optional bias+relu
  const size_t gbase = (size_t)node0 * IN;
  const size_t gmax  = (size_t)n_nodes * IN;
  for (int i = tid; i < NPB * IN / 4; i += 256) {
    size_t g = gbase + (size_t)i * 4;
    float4 v = make_float4(0.f, 0.f, 0.f, 0.f);
    if (g + 3 < gmax) {
      v = ((const float4*)X)[g / 4];
      if (PREB) {
        float4 bv = ((const float4*)preb)[i & (IN / 4 - 1)];
        v.x = fmaxf(v.x + bv.x, 0.f);
        v.y = fmaxf(v.y + bv.y, 0.f);
        v.z = fmaxf(v.z + bv.z, 0.f);
        v.w = fmaxf(v.w + bv.w, 0.f);
      }
    }
    ((float4*)xs)[i] = v;
  }
  __syncthreads();

  const int c  = tid & 63;   // output channel (lane)
  const int rg = tid >> 6;   // wave id -> row group
  float acc[8];
  #pragma unroll
  for (int j = 0; j < 8; ++j) acc[j] = 0.f;

  for (int k = 0; k < IN; k += 4) {
    float w0 = ws[k][c], w1 = ws[k+1][c], w2 = ws[k+2][c], w3 = ws[k+3][c];
    #pragma unroll
    for (int j = 0; j < 8; ++j) {
      float4 xv = *(const float4*)&xs[rg*8 + j][k];  // wave-broadcast
      acc[j] = fmaf(xv.x, w0, acc[j]);
      acc[j] = fmaf(xv.y, w1, acc[j]);
      acc[j] = fmaf(xv.z, w2, acc[j]);
      acc[j] = fmaf(xv.w, w3, acc[j]);
    }
  }
  #pragma unroll
  for (int j = 0; j < 8; ++j) {
    int node = node0 + rg*8 + j;
    if (node < n_nodes) Y[(size_t)node * 64 + c] = acc[j];
  }
}

// ---------------- Edge scatter-add: out[dst] += H[src], one wave per edge ----------------
__global__ __launch_bounds__(256) void scatter_kernel(
    const float* __restrict__ H, const int* __restrict__ ei,
    float* __restrict__ out, int n_edges) {
  int wid = (int)((blockIdx.x * 256u + (unsigned)threadIdx.x) >> 6);
  int c = threadIdx.x & 63;
  if (wid >= n_edges) return;
  int s = ei[wid];            // src (broadcast load)
  int d = ei[NE + wid];       // dst
  atomicAdd(&out[(size_t)d * 64 + c], H[(size_t)s * 64 + c]);
}

__device__ __forceinline__ int lb(const int* __restrict__ b, int n, int v) {
  int lo = 0, hi = n;
  while (lo < hi) { int mid = (lo + hi) >> 1; if (b[mid] < v) lo = mid + 1; else hi = mid; }
  return lo;
}

// ---------------- fused: relu(h+b2) -> mean-pool -> fc1(relu) -> fc2 -> log_softmax ----------------
// one block per graph; batch is sorted so graph g = rows [lb(g), lb(g+1))
__global__ __launch_bounds__(256) void pool_head_kernel(
    const float* __restrict__ h, const int* __restrict__ batch,
    const float* __restrict__ b2,
    const float* __restrict__ fc1w, const float* __restrict__ fc1b,
    const float* __restrict__ fc2w, const float* __restrict__ fc2b,
    float* __restrict__ out) {
  int g = blockIdx.x;
  int t = threadIdx.x;
  int c = t & 63, w = t >> 6;
  int start = lb(batch, NN, g);
  int end   = lb(batch, NN, g + 1);

  float bias = b2[c];
  float acc = 0.f;
  for (int node = start + w; node < end; node += 4) {
    float v = h[(size_t)node * 64 + c] + bias;   // coalesced 256B per wave
    acc += v > 0.f ? v : 0.f;
  }
  __shared__ float part[4][64];
  __shared__ float pooled[64];
  __shared__ float z1[32];
  __shared__ float z2[10];
  part[w][c] = acc;
  __syncthreads();
  if (t < 64) {
    float cnt = (float)(end - start);
    cnt = cnt > 1.f ? cnt : 1.f;
    pooled[t] = (part[0][t] + part[1][t] + part[2][t] + part[3][t]) / cnt;
  }
  __syncthreads();
  if (t < 32) {
    float a = fc1b[t];
    #pragma unroll
    for (int k = 0; k < 64; ++k) a = fmaf(pooled[k], fc1w[k * 32 + t], a);
    z1[t] = a > 0.f ? a : 0.f;
  }
  __syncthreads();
  if (t < 10) {
    float a = fc2b[t];
    #pragma unroll
    for (int k = 0; k < 32; ++k) a = fmaf(z1[k], fc2w[k * 10 + t], a);
    z2[t] = a;
  }
  __syncthreads();
  if (t == 0) {
    float m = z2[0];
    for (int i = 1; i < 10; ++i) m = fmaxf(m, z2[i]);
    float s = 0.f;
    for (int i = 0; i < 10; ++i) s += expf(z2[i] - m);
    float lse = logf(s) + m;
    for (int i = 0; i < 10; ++i) out[g * 10 + i] = z2[i] - lse;
  }
}

extern "C" void kernel_launch(void* const* d_in, const int* in_sizes, int n_in,
                              void* d_out, int out_size, void* d_ws, size_t ws_size,
                              hipStream_t stream) {
  const float* x    = (const float*)d_in[0];
  const int*   ei   = (const int*)  d_in[1];   // [2, NE] (src row, then dst row)
  const int*   bat  = (const int*)  d_in[2];
  const float* W1   = (const float*)d_in[3];
  const float* b1   = (const float*)d_in[4];
  const float* W2   = (const float*)d_in[5];
  const float* b2   = (const float*)d_in[6];
  const float* fc1w = (const float*)d_in[7];
  const float* fc1b = (const float*)d_in[8];
  const float* fc2w = (const float*)d_in[9];
  const float* fc2b = (const float*)d_in[10];
  float* out = (float*)d_out;

  char* ws = (char*)d_ws;
  float* A = (float*)ws;                // [NN,64] 12.8 MB
  float* B = (float*)(ws + 12800000);   // [NN,64] 12.8 MB

  const size_t HFEAT = (size_t)NN * 64;

  // ---- layer 1: A = x@W1 ; B = scatter(A) ----
  linear_kernel<128, false><<<(NN + 31) / 32, 256, 0, stream>>>(x, nullptr, W1, A, NN);
  hipMemsetAsync(B, 0, HFEAT * sizeof(float), stream);
  scatter_kernel<<<(NE * 64) / 256, 256, 0, stream>>>(A, ei, B, NE);

  // ---- layer 2: A = relu(B+b1)@W2 ; B = scatter(A) ----
  linear_kernel<64, true><<<(NN + 31) / 32, 256, 0, stream>>>(B, b1, W2, A, NN);
  hipMemsetAsync(B, 0, HFEAT * sizeof(float), stream);
  scatter_kernel<<<(NE * 64) / 256, 256, 0, stream>>>(A, ei, B, NE);

  // ---- fused pool + head (bias2+relu applied on read; no atomics) ----
  pool_head_kernel<<<NG, 256, 0, stream>>>(B, bat, b2, fc1w, fc1b, fc2w, fc2b, out);
}

// Round 3
// 544.886 us; speedup vs baseline: 1.6566x; 1.0869x over previous
//
#include <hip/hip_runtime.h>
#include <cstdint>
#include <cstddef>

#define NN 50000
#define NE 800000
#define NG 64

// ---------------- Linear: Y[n,64] = relu?(X + preb) @ W ----------------
template<int IN, bool PREB>
__global__ __launch_bounds__(256) void linear_kernel(
    const float* __restrict__ X, const float* __restrict__ preb,
    const float* __restrict__ W, float* __restrict__ Y, int n_nodes) {
  constexpr int OUT = 64;
  constexpr int NPB = 32;  // nodes per block
  __shared__ float xs[NPB][IN];
  __shared__ float ws[IN][OUT];
  const int tid = threadIdx.x;
  const int node0 = blockIdx.x * NPB;

  for (int i = tid; i < IN * OUT / 4; i += 256)
    ((float4*)ws)[i] = ((const float4*)W)[i];
  const size_t gbase = (size_t)node0 * IN;
  const size_t gmax  = (size_t)n_nodes * IN;
  for (int i = tid; i < NPB * IN / 4; i += 256) {
    size_t g = gbase + (size_t)i * 4;
    float4 v = make_float4(0.f, 0.f, 0.f, 0.f);
    if (g + 3 < gmax) {
      v = ((const float4*)X)[g / 4];
      if (PREB) {
        float4 bv = ((const float4*)preb)[i & (IN / 4 - 1)];
        v.x = fmaxf(v.x + bv.x, 0.f);
        v.y = fmaxf(v.y + bv.y, 0.f);
        v.z = fmaxf(v.z + bv.z, 0.f);
        v.w = fmaxf(v.w + bv.w, 0.f);
      }
    }
    ((float4*)xs)[i] = v;
  }
  __syncthreads();

  const int c  = tid & 63;
  const int rg = tid >> 6;
  float acc[8];
  #pragma unroll
  for (int j = 0; j < 8; ++j) acc[j] = 0.f;

  for (int k = 0; k < IN; k += 4) {
    float w0 = ws[k][c], w1 = ws[k+1][c], w2 = ws[k+2][c], w3 = ws[k+3][c];
    #pragma unroll
    for (int j = 0; j < 8; ++j) {
      float4 xv = *(const float4*)&xs[rg*8 + j][k];  // wave-broadcast
      acc[j] = fmaf(xv.x, w0, acc[j]);
      acc[j] = fmaf(xv.y, w1, acc[j]);
      acc[j] = fmaf(xv.z, w2, acc[j]);
      acc[j] = fmaf(xv.w, w3, acc[j]);
    }
  }
  #pragma unroll
  for (int j = 0; j < 8; ++j) {
    int node = node0 + rg*8 + j;
    if (node < n_nodes) Y[(size_t)node * 64 + c] = acc[j];
  }
}

// ---------------- CSR build ----------------
__global__ __launch_bounds__(256) void hist_kernel(
    const int* __restrict__ ei, int* __restrict__ deg) {
  int e = blockIdx.x * 256 + threadIdx.x;
  if (e < NE) atomicAdd(&deg[ei[NE + e]], 1);
}

// single-block exclusive scan over deg[NN] -> rowptr, cursor
__global__ __launch_bounds__(1024) void scan_kernel(
    const int* __restrict__ deg, int* __restrict__ rowptr, int* __restrict__ cursor) {
  constexpr int CH = (NN + 1023) / 1024;  // 49
  int t = threadIdx.x;
  int base = t * CH;
  int sum = 0;
  #pragma unroll
  for (int i = 0; i < CH; ++i) {
    int idx = base + i;
    if (idx < NN) sum += deg[idx];
  }
  __shared__ int ps[1024];
  ps[t] = sum;
  __syncthreads();
  for (int off = 1; off < 1024; off <<= 1) {
    int v = (t >= off) ? ps[t - off] : 0;
    __syncthreads();
    ps[t] += v;
    __syncthreads();
  }
  int run = (t == 0) ? 0 : ps[t - 1];
  #pragma unroll
  for (int i = 0; i < CH; ++i) {
    int idx = base + i;
    if (idx < NN) {
      rowptr[idx] = run;
      cursor[idx] = run;
      run += deg[idx];
    }
  }
  if (t == 0) rowptr[NN] = NE;
}

__global__ __launch_bounds__(256) void fill_kernel(
    const int* __restrict__ ei, int* __restrict__ cursor, int* __restrict__ srcs) {
  int e = blockIdx.x * 256 + threadIdx.x;
  if (e >= NE) return;
  int d = ei[NE + e];
  int pos = atomicAdd(&cursor[d], 1);
  srcs[pos] = ei[e];
}

// ---------------- gather-aggregate: B[n] = sum_{e: dst==n} A[src(e)] ----------------
__global__ __launch_bounds__(256) void gather_kernel(
    const float* __restrict__ A, const int* __restrict__ rowptr,
    const int* __restrict__ srcs, float* __restrict__ B) {
  int wid = (int)((blockIdx.x * 256u + (unsigned)threadIdx.x) >> 6);
  int c = threadIdx.x & 63;
  if (wid >= NN) return;
  int beg = rowptr[wid], end = rowptr[wid + 1];
  float acc0 = 0.f, acc1 = 0.f;
  int i = beg;
  for (; i + 1 < end; i += 2) {
    int s0 = srcs[i], s1 = srcs[i + 1];   // wave-broadcast loads
    acc0 += A[(size_t)s0 * 64 + c];
    acc1 += A[(size_t)s1 * 64 + c];
  }
  if (i < end) acc0 += A[(size_t)srcs[i] * 64 + c];
  B[(size_t)wid * 64 + c] = acc0 + acc1;
}

__device__ __forceinline__ int lb(const int* __restrict__ b, int n, int v) {
  int lo = 0, hi = n;
  while (lo < hi) { int mid = (lo + hi) >> 1; if (b[mid] < v) lo = mid + 1; else hi = mid; }
  return lo;
}

// ---------------- fused: relu(h+b2) -> mean-pool -> fc1(relu) -> fc2 -> log_softmax ----------------
__global__ __launch_bounds__(256) void pool_head_kernel(
    const float* __restrict__ h, const int* __restrict__ batch,
    const float* __restrict__ b2,
    const float* __restrict__ fc1w, const float* __restrict__ fc1b,
    const float* __restrict__ fc2w, const float* __restrict__ fc2b,
    float* __restrict__ out) {
  int g = blockIdx.x;
  int t = threadIdx.x;
  int c = t & 63, w = t >> 6;
  int start = lb(batch, NN, g);
  int end   = lb(batch, NN, g + 1);

  float bias = b2[c];
  float acc = 0.f;
  for (int node = start + w; node < end; node += 4) {
    float v = h[(size_t)node * 64 + c] + bias;
    acc += v > 0.f ? v : 0.f;
  }
  __shared__ float part[4][64];
  __shared__ float pooled[64];
  __shared__ float z1[32];
  __shared__ float z2[10];
  part[w][c] = acc;
  __syncthreads();
  if (t < 64) {
    float cnt = (float)(end - start);
    cnt = cnt > 1.f ? cnt : 1.f;
    pooled[t] = (part[0][t] + part[1][t] + part[2][t] + part[3][t]) / cnt;
  }
  __syncthreads();
  if (t < 32) {
    float a = fc1b[t];
    #pragma unroll
    for (int k = 0; k < 64; ++k) a = fmaf(pooled[k], fc1w[k * 32 + t], a);
    z1[t] = a > 0.f ? a : 0.f;
  }
  __syncthreads();
  if (t < 10) {
    float a = fc2b[t];
    #pragma unroll
    for (int k = 0; k < 32; ++k) a = fmaf(z1[k], fc2w[k * 10 + t], a);
    z2[t] = a;
  }
  __syncthreads();
  if (t == 0) {
    float m = z2[0];
    for (int i = 1; i < 10; ++i) m = fmaxf(m, z2[i]);
    float s = 0.f;
    for (int i = 0; i < 10; ++i) s += expf(z2[i] - m);
    float lse = logf(s) + m;
    for (int i = 0; i < 10; ++i) out[g * 10 + i] = z2[i] - lse;
  }
}

extern "C" void kernel_launch(void* const* d_in, const int* in_sizes, int n_in,
                              void* d_out, int out_size, void* d_ws, size_t ws_size,
                              hipStream_t stream) {
  const float* x    = (const float*)d_in[0];
  const int*   ei   = (const int*)  d_in[1];   // [2, NE]
  const int*   bat  = (const int*)  d_in[2];
  const float* W1   = (const float*)d_in[3];
  const float* b1   = (const float*)d_in[4];
  const float* W2   = (const float*)d_in[5];
  const float* b2   = (const float*)d_in[6];
  const float* fc1w = (const float*)d_in[7];
  const float* fc1b = (const float*)d_in[8];
  const float* fc2w = (const float*)d_in[9];
  const float* fc2b = (const float*)d_in[10];
  float* out = (float*)d_out;

  char* ws = (char*)d_ws;
  float* A      = (float*)ws;                         // [NN,64]   12.8 MB
  float* B      = (float*)(ws + 12800000);            // [NN,64]   12.8 MB
  int*   rowptr = (int*)  (ws + 25600000);            // [NN+1]
  int*   cursor = (int*)  (ws + 25600000 + 4*(NN+1)); // [NN]
  int*   deg    = (int*)  (ws + 25600000 + 4*(2*NN+1));// [NN]
  int*   srcs   = (int*)  (ws + 25600000 + 4*(3*NN+1));// [NE]

  // ---- CSR build (counting sort by dst), shared by both layers ----
  hipMemsetAsync(deg, 0, NN * sizeof(int), stream);
  hist_kernel<<<(NE + 255) / 256, 256, 0, stream>>>(ei, deg);
  scan_kernel<<<1, 1024, 0, stream>>>(deg, rowptr, cursor);
  fill_kernel<<<(NE + 255) / 256, 256, 0, stream>>>(ei, cursor, srcs);

  // ---- layer 1: A = x@W1 ; B = gather(A) ----
  linear_kernel<128, false><<<(NN + 31) / 32, 256, 0, stream>>>(x, nullptr, W1, A, NN);
  gather_kernel<<<(NN * 64 + 255) / 256, 256, 0, stream>>>(A, rowptr, srcs, B);

  // ---- layer 2: A = relu(B+b1)@W2 ; B = gather(A) ----
  linear_kernel<64, true><<<(NN + 31) / 32, 256, 0, stream>>>(B, b1, W2, A, NN);
  gather_kernel<<<(NN * 64 + 255) / 256, 256, 0, stream>>>(A, rowptr, srcs, B);

  // ---- fused pool + head ----
  pool_head_kernel<<<NG, 256, 0, stream>>>(B, bat, b2, fc1w, fc1b, fc2w, fc2b, out);
}

// Round 4
// 387.690 us; speedup vs baseline: 2.3284x; 1.4055x over previous
//
#include <hip/hip_runtime.h>
#include <cstdint>
#include <cstddef>

#define NN 50000
#define NE 800000
#define NG 64
#define NB 196  // ceil(NN/256)

// ---------------- Linear: Y[n,64] = relu?(X + preb) @ W ----------------
template<int IN, bool PREB>
__global__ __launch_bounds__(256) void linear_kernel(
    const float* __restrict__ X, const float* __restrict__ preb,
    const float* __restrict__ W, float* __restrict__ Y, int n_nodes) {
  constexpr int OUT = 64;
  constexpr int NPB = 32;  // nodes per block
  __shared__ float xs[NPB][IN];
  __shared__ float ws[IN][OUT];
  const int tid = threadIdx.x;
  const int node0 = blockIdx.x * NPB;

  for (int i = tid; i < IN * OUT / 4; i += 256)
    ((float4*)ws)[i] = ((const float4*)W)[i];
  const size_t gbase = (size_t)node0 * IN;
  const size_t gmax  = (size_t)n_nodes * IN;
  for (int i = tid; i < NPB * IN / 4; i += 256) {
    size_t g = gbase + (size_t)i * 4;
    float4 v = make_float4(0.f, 0.f, 0.f, 0.f);
    if (g + 3 < gmax) {
      v = ((const float4*)X)[g / 4];
      if (PREB) {
        float4 bv = ((const float4*)preb)[i & (IN / 4 - 1)];
        v.x = fmaxf(v.x + bv.x, 0.f);
        v.y = fmaxf(v.y + bv.y, 0.f);
        v.z = fmaxf(v.z + bv.z, 0.f);
        v.w = fmaxf(v.w + bv.w, 0.f);
      }
    }
    ((float4*)xs)[i] = v;
  }
  __syncthreads();

  const int c  = tid & 63;
  const int rg = tid >> 6;
  float acc[8];
  #pragma unroll
  for (int j = 0; j < 8; ++j) acc[j] = 0.f;

  for (int k = 0; k < IN; k += 4) {
    float w0 = ws[k][c], w1 = ws[k+1][c], w2 = ws[k+2][c], w3 = ws[k+3][c];
    #pragma unroll
    for (int j = 0; j < 8; ++j) {
      float4 xv = *(const float4*)&xs[rg*8 + j][k];  // wave-broadcast
      acc[j] = fmaf(xv.x, w0, acc[j]);
      acc[j] = fmaf(xv.y, w1, acc[j]);
      acc[j] = fmaf(xv.z, w2, acc[j]);
      acc[j] = fmaf(xv.w, w3, acc[j]);
    }
  }
  #pragma unroll
  for (int j = 0; j < 8; ++j) {
    int node = node0 + rg*8 + j;
    if (node < n_nodes) Y[(size_t)node * 64 + c] = acc[j];
  }
}

// ---------------- CSR build ----------------
__global__ __launch_bounds__(256) void hist_kernel(
    const int* __restrict__ ei, int* __restrict__ deg) {
  int e = blockIdx.x * 256 + threadIdx.x;
  if (e < NE) atomicAdd(&deg[ei[NE + e]], 1);
}

// stage 1: per-block sums of deg
__global__ __launch_bounds__(256) void block_sum_kernel(
    const int* __restrict__ deg, int* __restrict__ bsums) {
  int idx = blockIdx.x * 256 + threadIdx.x;
  int v = (idx < NN) ? deg[idx] : 0;
  #pragma unroll
  for (int off = 32; off; off >>= 1) v += __shfl_down(v, off, 64);
  __shared__ int wsum[4];
  if ((threadIdx.x & 63) == 0) wsum[threadIdx.x >> 6] = v;
  __syncthreads();
  if (threadIdx.x == 0) bsums[blockIdx.x] = wsum[0] + wsum[1] + wsum[2] + wsum[3];
}

// stage 2: exclusive scan of 196 block sums (one block)
__global__ __launch_bounds__(256) void scan_bsums_kernel(
    const int* __restrict__ bsums, int* __restrict__ boffs) {
  int t = threadIdx.x;
  int v = (t < NB) ? bsums[t] : 0;
  __shared__ int ps[256];
  ps[t] = v;
  __syncthreads();
  for (int off = 1; off < 256; off <<= 1) {
    int add = (t >= off) ? ps[t - off] : 0;
    __syncthreads();
    ps[t] += add;
    __syncthreads();
  }
  boffs[t] = ps[t] - v;  // exclusive
}

// stage 3: block-local exclusive scan + global offset -> rowptr, cursor
__global__ __launch_bounds__(256) void scan_write_kernel(
    const int* __restrict__ deg, const int* __restrict__ boffs,
    int* __restrict__ rowptr, int* __restrict__ cursor) {
  int t = threadIdx.x;
  int idx = blockIdx.x * 256 + t;
  int v = (idx < NN) ? deg[idx] : 0;
  __shared__ int ps[256];
  ps[t] = v;
  __syncthreads();
  for (int off = 1; off < 256; off <<= 1) {
    int add = (t >= off) ? ps[t - off] : 0;
    __syncthreads();
    ps[t] += add;
    __syncthreads();
  }
  int ex = ps[t] - v + boffs[blockIdx.x];
  if (idx < NN) { rowptr[idx] = ex; cursor[idx] = ex; }
  if (idx == NN) rowptr[NN] = NE;
}

__global__ __launch_bounds__(256) void fill_kernel(
    const int* __restrict__ ei, int* __restrict__ cursor, int* __restrict__ srcs) {
  int e = blockIdx.x * 256 + threadIdx.x;
  if (e >= NE) return;
  int d = ei[NE + e];
  int pos = atomicAdd(&cursor[d], 1);
  srcs[pos] = ei[e];
}

// ---------------- gather-aggregate v2: 4 nodes/wave, float4/lane ----------------
__global__ __launch_bounds__(256) void gather4_kernel(
    const float* __restrict__ A, const int* __restrict__ rowptr,
    const int* __restrict__ srcs, float* __restrict__ B) {
  int lane = threadIdx.x & 63;
  int grp  = lane >> 4;    // 0..3: node within wave
  int sub  = lane & 15;    // float4 slot within row
  int wid  = (int)((blockIdx.x * 256u + (unsigned)threadIdx.x) >> 6);
  int node = wid * 4 + grp;
  if (node >= NN) return;
  int beg = rowptr[node], end = rowptr[node + 1];
  const float4* A4 = (const float4*)A;
  float4 a0 = make_float4(0.f, 0.f, 0.f, 0.f);
  float4 a1 = make_float4(0.f, 0.f, 0.f, 0.f);
  int i = beg;
  for (; i + 1 < end; i += 2) {
    int s0 = srcs[i], s1 = srcs[i + 1];
    float4 v0 = A4[(size_t)s0 * 16 + sub];
    float4 v1 = A4[(size_t)s1 * 16 + sub];
    a0.x += v0.x; a0.y += v0.y; a0.z += v0.z; a0.w += v0.w;
    a1.x += v1.x; a1.y += v1.y; a1.z += v1.z; a1.w += v1.w;
  }
  if (i < end) {
    float4 v = A4[(size_t)srcs[i] * 16 + sub];
    a0.x += v.x; a0.y += v.y; a0.z += v.z; a0.w += v.w;
  }
  float4 r = make_float4(a0.x + a1.x, a0.y + a1.y, a0.z + a1.z, a0.w + a1.w);
  ((float4*)B)[(size_t)node * 16 + sub] = r;
}

__device__ __forceinline__ int lb(const int* __restrict__ b, int n, int v) {
  int lo = 0, hi = n;
  while (lo < hi) { int mid = (lo + hi) >> 1; if (b[mid] < v) lo = mid + 1; else hi = mid; }
  return lo;
}

// ---------------- fused: relu(h+b2) -> mean-pool -> fc1(relu) -> fc2 -> log_softmax ----------------
__global__ __launch_bounds__(256) void pool_head_kernel(
    const float* __restrict__ h, const int* __restrict__ batch,
    const float* __restrict__ b2,
    const float* __restrict__ fc1w, const float* __restrict__ fc1b,
    const float* __restrict__ fc2w, const float* __restrict__ fc2b,
    float* __restrict__ out) {
  int g = blockIdx.x;
  int t = threadIdx.x;
  int c = t & 63, w = t >> 6;
  int start = lb(batch, NN, g);
  int end   = lb(batch, NN, g + 1);

  float bias = b2[c];
  float acc = 0.f;
  for (int node = start + w; node < end; node += 4) {
    float v = h[(size_t)node * 64 + c] + bias;
    acc += v > 0.f ? v : 0.f;
  }
  __shared__ float part[4][64];
  __shared__ float pooled[64];
  __shared__ float z1[32];
  __shared__ float z2[10];
  part[w][c] = acc;
  __syncthreads();
  if (t < 64) {
    float cnt = (float)(end - start);
    cnt = cnt > 1.f ? cnt : 1.f;
    pooled[t] = (part[0][t] + part[1][t] + part[2][t] + part[3][t]) / cnt;
  }
  __syncthreads();
  if (t < 32) {
    float a = fc1b[t];
    #pragma unroll
    for (int k = 0; k < 64; ++k) a = fmaf(pooled[k], fc1w[k * 32 + t], a);
    z1[t] = a > 0.f ? a : 0.f;
  }
  __syncthreads();
  if (t < 10) {
    float a = fc2b[t];
    #pragma unroll
    for (int k = 0; k < 32; ++k) a = fmaf(z1[k], fc2w[k * 10 + t], a);
    z2[t] = a;
  }
  __syncthreads();
  if (t == 0) {
    float m = z2[0];
    for (int i = 1; i < 10; ++i) m = fmaxf(m, z2[i]);
    float s = 0.f;
    for (int i = 0; i < 10; ++i) s += expf(z2[i] - m);
    float lse = logf(s) + m;
    for (int i = 0; i < 10; ++i) out[g * 10 + i] = z2[i] - lse;
  }
}

extern "C" void kernel_launch(void* const* d_in, const int* in_sizes, int n_in,
                              void* d_out, int out_size, void* d_ws, size_t ws_size,
                              hipStream_t stream) {
  const float* x    = (const float*)d_in[0];
  const int*   ei   = (const int*)  d_in[1];   // [2, NE]
  const int*   bat  = (const int*)  d_in[2];
  const float* W1   = (const float*)d_in[3];
  const float* b1   = (const float*)d_in[4];
  const float* W2   = (const float*)d_in[5];
  const float* b2   = (const float*)d_in[6];
  const float* fc1w = (const float*)d_in[7];
  const float* fc1b = (const float*)d_in[8];
  const float* fc2w = (const float*)d_in[9];
  const float* fc2b = (const float*)d_in[10];
  float* out = (float*)d_out;

  char* ws = (char*)d_ws;
  float* A      = (float*)ws;                           // [NN,64]   12.8 MB
  float* B      = (float*)(ws + 12800000);              // [NN,64]   12.8 MB
  int*   rowptr = (int*)  (ws + 25600000);              // [NN+1]
  int*   cursor = (int*)  (ws + 25600000 + 4*(NN+1));   // [NN]
  int*   deg    = (int*)  (ws + 25600000 + 4*(2*NN+1)); // [NN]
  int*   srcs   = (int*)  (ws + 25600000 + 4*(3*NN+1)); // [NE]
  int*   bsums  = (int*)  (ws + 25600000 + 4*(3*NN+1) + 4*NE);       // [256]
  int*   boffs  = (int*)  (ws + 25600000 + 4*(3*NN+1) + 4*NE + 1024);// [256]

  // ---- CSR build (counting sort by dst), shared by both layers ----
  hipMemsetAsync(deg, 0, NN * sizeof(int), stream);
  hist_kernel<<<(NE + 255) / 256, 256, 0, stream>>>(ei, deg);
  block_sum_kernel<<<NB, 256, 0, stream>>>(deg, bsums);
  scan_bsums_kernel<<<1, 256, 0, stream>>>(bsums, boffs);
  scan_write_kernel<<<NB, 256, 0, stream>>>(deg, boffs, rowptr, cursor);
  fill_kernel<<<(NE + 255) / 256, 256, 0, stream>>>(ei, cursor, srcs);

  // ---- layer 1: A = x@W1 ; B = gather(A) ----
  linear_kernel<128, false><<<(NN + 31) / 32, 256, 0, stream>>>(x, nullptr, W1, A, NN);
  gather4_kernel<<<((NN + 3) / 4 * 64 + 255) / 256, 256, 0, stream>>>(A, rowptr, srcs, B);

  // ---- layer 2: A = relu(B+b1)@W2 ; B = gather(A) ----
  linear_kernel<64, true><<<(NN + 31) / 32, 256, 0, stream>>>(B, b1, W2, A, NN);
  gather4_kernel<<<((NN + 3) / 4 * 64 + 255) / 256, 256, 0, stream>>>(A, rowptr, srcs, B);

  // ---- fused pool + head ----
  pool_head_kernel<<<NG, 256, 0, stream>>>(B, bat, b2, fc1w, fc1b, fc2w, fc2b, out);
}

// Round 5
// 356.120 us; speedup vs baseline: 2.5348x; 1.0886x over previous
//
#include <hip/hip_runtime.h>
#include <cstdint>
#include <cstddef>

#define NN 50000
#define NE 800000
#define NG 64
#define NB 196  // ceil(NN/256)

// ---------------- Linear: Y[n,64] = relu?(X + preb) @ W ----------------
template<int IN, bool PREB>
__global__ __launch_bounds__(256) void linear_kernel(
    const float* __restrict__ X, const float* __restrict__ preb,
    const float* __restrict__ W, float* __restrict__ Y, int n_nodes) {
  constexpr int OUT = 64;
  constexpr int NPB = 32;  // nodes per block
  __shared__ float xs[NPB][IN];
  __shared__ float ws[IN][OUT];
  const int tid = threadIdx.x;
  const int node0 = blockIdx.x * NPB;

  for (int i = tid; i < IN * OUT / 4; i += 256)
    ((float4*)ws)[i] = ((const float4*)W)[i];
  const size_t gbase = (size_t)node0 * IN;
  const size_t gmax  = (size_t)n_nodes * IN;
  for (int i = tid; i < NPB * IN / 4; i += 256) {
    size_t g = gbase + (size_t)i * 4;
    float4 v = make_float4(0.f, 0.f, 0.f, 0.f);
    if (g + 3 < gmax) {
      v = ((const float4*)X)[g / 4];
      if (PREB) {
        float4 bv = ((const float4*)preb)[i & (IN / 4 - 1)];
        v.x = fmaxf(v.x + bv.x, 0.f);
        v.y = fmaxf(v.y + bv.y, 0.f);
        v.z = fmaxf(v.z + bv.z, 0.f);
        v.w = fmaxf(v.w + bv.w, 0.f);
      }
    }
    ((float4*)xs)[i] = v;
  }
  __syncthreads();

  const int c  = tid & 63;
  const int rg = tid >> 6;
  float acc[8];
  #pragma unroll
  for (int j = 0; j < 8; ++j) acc[j] = 0.f;

  for (int k = 0; k < IN; k += 4) {
    float w0 = ws[k][c], w1 = ws[k+1][c], w2 = ws[k+2][c], w3 = ws[k+3][c];
    #pragma unroll
    for (int j = 0; j < 8; ++j) {
      float4 xv = *(const float4*)&xs[rg*8 + j][k];  // wave-broadcast
      acc[j] = fmaf(xv.x, w0, acc[j]);
      acc[j] = fmaf(xv.y, w1, acc[j]);
      acc[j] = fmaf(xv.z, w2, acc[j]);
      acc[j] = fmaf(xv.w, w3, acc[j]);
    }
  }
  #pragma unroll
  for (int j = 0; j < 8; ++j) {
    int node = node0 + rg*8 + j;
    if (node < n_nodes) Y[(size_t)node * 64 + c] = acc[j];
  }
}

// ---------------- CSR build ----------------
__global__ __launch_bounds__(256) void hist_kernel(
    const int* __restrict__ ei, int* __restrict__ deg) {
  int e = blockIdx.x * 256 + threadIdx.x;
  if (e < NE) atomicAdd(&deg[ei[NE + e]], 1);
}

__global__ __launch_bounds__(256) void block_sum_kernel(
    const int* __restrict__ deg, int* __restrict__ bsums) {
  int idx = blockIdx.x * 256 + threadIdx.x;
  int v = (idx < NN) ? deg[idx] : 0;
  #pragma unroll
  for (int off = 32; off; off >>= 1) v += __shfl_down(v, off, 64);
  __shared__ int wsum[4];
  if ((threadIdx.x & 63) == 0) wsum[threadIdx.x >> 6] = v;
  __syncthreads();
  if (threadIdx.x == 0) bsums[blockIdx.x] = wsum[0] + wsum[1] + wsum[2] + wsum[3];
}

__global__ __launch_bounds__(256) void scan_bsums_kernel(
    const int* __restrict__ bsums, int* __restrict__ boffs) {
  int t = threadIdx.x;
  int v = (t < NB) ? bsums[t] : 0;
  __shared__ int ps[256];
  ps[t] = v;
  __syncthreads();
  for (int off = 1; off < 256; off <<= 1) {
    int add = (t >= off) ? ps[t - off] : 0;
    __syncthreads();
    ps[t] += add;
    __syncthreads();
  }
  boffs[t] = ps[t] - v;  // exclusive
}

__global__ __launch_bounds__(256) void scan_write_kernel(
    const int* __restrict__ deg, const int* __restrict__ boffs,
    int* __restrict__ rowptr, int* __restrict__ cursor) {
  int t = threadIdx.x;
  int idx = blockIdx.x * 256 + t;
  int v = (idx < NN) ? deg[idx] : 0;
  __shared__ int ps[256];
  ps[t] = v;
  __syncthreads();
  for (int off = 1; off < 256; off <<= 1) {
    int add = (t >= off) ? ps[t - off] : 0;
    __syncthreads();
    ps[t] += add;
    __syncthreads();
  }
  int ex = ps[t] - v + boffs[blockIdx.x];
  if (idx < NN) { rowptr[idx] = ex; cursor[idx] = ex; }
  if (idx == NN) rowptr[NN] = NE;
}

__global__ __launch_bounds__(256) void fill_kernel(
    const int* __restrict__ ei, int* __restrict__ cursor, int* __restrict__ srcs) {
  int e = blockIdx.x * 256 + threadIdx.x;
  if (e >= NE) return;
  int d = ei[NE + e];
  int pos = atomicAdd(&cursor[d], 1);
  srcs[pos] = ei[e];
}

// ---------------- gather-aggregate: 4 nodes/wave, float4/lane ----------------
__global__ __launch_bounds__(256) void gather4_kernel(
    const float* __restrict__ A, const int* __restrict__ rowptr,
    const int* __restrict__ srcs, float* __restrict__ B) {
  int lane = threadIdx.x & 63;
  int grp  = lane >> 4;    // 0..3: node within wave
  int sub  = lane & 15;    // float4 slot within row
  int wid  = (int)((blockIdx.x * 256u + (unsigned)threadIdx.x) >> 6);
  int node = wid * 4 + grp;
  if (node >= NN) return;
  int beg = rowptr[node], end = rowptr[node + 1];
  const float4* A4 = (const float4*)A;
  float4 a0 = make_float4(0.f, 0.f, 0.f, 0.f);
  float4 a1 = make_float4(0.f, 0.f, 0.f, 0.f);
  int i = beg;
  for (; i + 1 < end; i += 2) {
    int s0 = srcs[i], s1 = srcs[i + 1];
    float4 v0 = A4[(size_t)s0 * 16 + sub];
    float4 v1 = A4[(size_t)s1 * 16 + sub];
    a0.x += v0.x; a0.y += v0.y; a0.z += v0.z; a0.w += v0.w;
    a1.x += v1.x; a1.y += v1.y; a1.z += v1.z; a1.w += v1.w;
  }
  if (i < end) {
    float4 v = A4[(size_t)srcs[i] * 16 + sub];
    a0.x += v.x; a0.y += v.y; a0.z += v.z; a0.w += v.w;
  }
  float4 r = make_float4(a0.x + a1.x, a0.y + a1.y, a0.z + a1.z, a0.w + a1.w);
  ((float4*)B)[(size_t)node * 16 + sub] = r;
}

__device__ __forceinline__ int lb(const int* __restrict__ b, int n, int v) {
  int lo = 0, hi = n;
  while (lo < hi) { int mid = (lo + hi) >> 1; if (b[mid] < v) lo = mid + 1; else hi = mid; }
  return lo;
}

// ---------------- pool stage 1: grid-parallel partial sums ----------------
// each block covers 128 contiguous nodes; each wave a 32-row strip.
// batch sorted -> flush one atomicAdd round per graph-transition per wave.
__global__ __launch_bounds__(256) void pool_partial_kernel(
    const float* __restrict__ h, const int* __restrict__ batch,
    const float* __restrict__ b2, float* __restrict__ sums) {
  int c = threadIdx.x & 63, w = threadIdx.x >> 6;
  int n0 = blockIdx.x * 128 + w * 32;
  float bias = b2[c];
  float acc = 0.f;
  int curg = -1;
  #pragma unroll 4
  for (int i = 0; i < 32; ++i) {
    int node = n0 + i;
    if (node >= NN) break;
    int g = batch[node];              // wave-uniform
    if (g != curg) {
      if (curg >= 0) atomicAdd(&sums[curg * 64 + c], acc);
      curg = g; acc = 0.f;
    }
    float v = h[(size_t)node * 64 + c] + bias;   // coalesced 256B/wave
    acc += v > 0.f ? v : 0.f;
  }
  if (curg >= 0) atomicAdd(&sums[curg * 64 + c], acc);
}

// ---------------- pool stage 2 + head: tiny ----------------
__global__ __launch_bounds__(64) void head_kernel(
    const float* __restrict__ sums, const int* __restrict__ batch,
    const float* __restrict__ fc1w, const float* __restrict__ fc1b,
    const float* __restrict__ fc2w, const float* __restrict__ fc2b,
    float* __restrict__ out) {
  int g = blockIdx.x;
  int t = threadIdx.x;
  __shared__ float pooled[64];
  __shared__ float z1[32];
  __shared__ float z2[10];
  int start = lb(batch, NN, g);
  int end   = lb(batch, NN, g + 1);
  float cnt = (float)(end - start);
  cnt = cnt > 1.f ? cnt : 1.f;
  pooled[t] = sums[g * 64 + t] / cnt;
  __syncthreads();
  if (t < 32) {
    float a = fc1b[t];
    #pragma unroll
    for (int k = 0; k < 64; ++k) a = fmaf(pooled[k], fc1w[k * 32 + t], a);
    z1[t] = a > 0.f ? a : 0.f;
  }
  __syncthreads();
  if (t < 10) {
    float a = fc2b[t];
    #pragma unroll
    for (int k = 0; k < 32; ++k) a = fmaf(z1[k], fc2w[k * 10 + t], a);
    z2[t] = a;
  }
  __syncthreads();
  if (t == 0) {
    float m = z2[0];
    for (int i = 1; i < 10; ++i) m = fmaxf(m, z2[i]);
    float s = 0.f;
    for (int i = 0; i < 10; ++i) s += expf(z2[i] - m);
    float lse = logf(s) + m;
    for (int i = 0; i < 10; ++i) out[g * 10 + i] = z2[i] - lse;
  }
}

extern "C" void kernel_launch(void* const* d_in, const int* in_sizes, int n_in,
                              void* d_out, int out_size, void* d_ws, size_t ws_size,
                              hipStream_t stream) {
  const float* x    = (const float*)d_in[0];
  const int*   ei   = (const int*)  d_in[1];   // [2, NE]
  const int*   bat  = (const int*)  d_in[2];
  const float* W1   = (const float*)d_in[3];
  const float* b1   = (const float*)d_in[4];
  const float* W2   = (const float*)d_in[5];
  const float* b2   = (const float*)d_in[6];
  const float* fc1w = (const float*)d_in[7];
  const float* fc1b = (const float*)d_in[8];
  const float* fc2w = (const float*)d_in[9];
  const float* fc2b = (const float*)d_in[10];
  float* out = (float*)d_out;

  char* ws = (char*)d_ws;
  float* A      = (float*)ws;                           // [NN,64]   12.8 MB
  float* B      = (float*)(ws + 12800000);              // [NN,64]   12.8 MB
  int*   rowptr = (int*)  (ws + 25600000);              // [NN+1]
  int*   cursor = (int*)  (ws + 25600000 + 4*(NN+1));   // [NN]
  int*   deg    = (int*)  (ws + 25600000 + 4*(2*NN+1)); // [NN]
  int*   srcs   = (int*)  (ws + 25600000 + 4*(3*NN+1)); // [NE]
  int*   bsums  = (int*)  (ws + 25600000 + 4*(3*NN+1) + 4*NE);        // [256]
  int*   boffs  = (int*)  (ws + 25600000 + 4*(3*NN+1) + 4*NE + 1024); // [256]
  float* sums   = (float*)(ws + 25600000 + 4*(3*NN+1) + 4*NE + 2048); // [NG,64]

  // ---- CSR build (counting sort by dst), shared by both layers ----
  hipMemsetAsync(deg, 0, NN * sizeof(int), stream);
  hist_kernel<<<(NE + 255) / 256, 256, 0, stream>>>(ei, deg);
  block_sum_kernel<<<NB, 256, 0, stream>>>(deg, bsums);
  scan_bsums_kernel<<<1, 256, 0, stream>>>(bsums, boffs);
  scan_write_kernel<<<NB, 256, 0, stream>>>(deg, boffs, rowptr, cursor);
  fill_kernel<<<(NE + 255) / 256, 256, 0, stream>>>(ei, cursor, srcs);

  // ---- layer 1: A = x@W1 ; B = gather(A) ----
  linear_kernel<128, false><<<(NN + 31) / 32, 256, 0, stream>>>(x, nullptr, W1, A, NN);
  gather4_kernel<<<3125, 256, 0, stream>>>(A, rowptr, srcs, B);

  // ---- layer 2: A = relu(B+b1)@W2 ; B = gather(A) ----
  linear_kernel<64, true><<<(NN + 31) / 32, 256, 0, stream>>>(B, b1, W2, A, NN);
  gather4_kernel<<<3125, 256, 0, stream>>>(A, rowptr, srcs, B);

  // ---- pool (partial sums, no serial per-graph walk) + head ----
  hipMemsetAsync(sums, 0, NG * 64 * sizeof(float), stream);
  pool_partial_kernel<<<(NN + 127) / 128, 256, 0, stream>>>(B, bat, b2, sums);
  head_kernel<<<NG, 64, 0, stream>>>(sums, bat, fc1w, fc1b, fc2w, fc2b, out);
}

// Round 6
// 318.168 us; speedup vs baseline: 2.8371x; 1.1193x over previous
//
#include <hip/hip_runtime.h>
#include <cstdint>
#include <cstddef>

#define NN 50000
#define NE 800000
#define NG 64
#define NB 196  // ceil(NN/256)

// ---------------- Linear: Y[n,64] = relu?(X + preb) @ W ----------------
// W staged transposed+padded: wsT[c][k]; lane c reads float4 over k (1 ds_read_b128,
// row stride IN+4 dwords == 4 mod 32 -> uniform banks). X rows read as wave-broadcast
// float4. launch_bounds(256,4) caps VGPR<=128: R5 showed VGPR=256 + 107MB scratch-spill
// writes when the allocator was left unbounded.
template<int IN, bool PREB>
__global__ __launch_bounds__(256, 4) void linear_kernel(
    const float* __restrict__ X, const float* __restrict__ preb,
    const float* __restrict__ W, float* __restrict__ Y, int n_nodes) {
  constexpr int NPB = 32;  // nodes per block
  __shared__ float xs[NPB][IN];
  __shared__ float wsT[64][IN + 4];
  const int tid = threadIdx.x;
  const int node0 = blockIdx.x * NPB;

  // stage W transposed (global read coalesced float4; LDS scalar writes, once/block)
  for (int i = tid; i < IN * 16; i += 256) {
    float4 v = ((const float4*)W)[i];
    int k  = i >> 4;          // W row (k index)
    int c0 = (i & 15) << 2;   // W col (channel)
    wsT[c0 + 0][k] = v.x;
    wsT[c0 + 1][k] = v.y;
    wsT[c0 + 2][k] = v.z;
    wsT[c0 + 3][k] = v.w;
  }
  // stage X rows (contiguous; zero-fill OOB tail), optional fused bias+relu
  const size_t gbase = (size_t)node0 * IN;
  const size_t gmax  = (size_t)n_nodes * IN;
  for (int i = tid; i < NPB * IN / 4; i += 256) {
    size_t g = gbase + (size_t)i * 4;
    float4 v = make_float4(0.f, 0.f, 0.f, 0.f);
    if (g + 3 < gmax) {
      v = ((const float4*)X)[g / 4];
      if (PREB) {
        float4 bv = ((const float4*)preb)[i & (IN / 4 - 1)];
        v.x = fmaxf(v.x + bv.x, 0.f);
        v.y = fmaxf(v.y + bv.y, 0.f);
        v.z = fmaxf(v.z + bv.z, 0.f);
        v.w = fmaxf(v.w + bv.w, 0.f);
      }
    }
    ((float4*)xs)[i] = v;
  }
  __syncthreads();

  const int c  = tid & 63;   // output channel (lane)
  const int rg = tid >> 6;   // wave id -> row group (8 nodes)
  float acc[8];
  #pragma unroll
  for (int j = 0; j < 8; ++j) acc[j] = 0.f;

  #pragma unroll 2
  for (int k4 = 0; k4 < IN / 4; ++k4) {
    const float4 wv = *(const float4*)&wsT[c][k4 * 4];   // 1 b128, conflict-free
    #pragma unroll
    for (int j = 0; j < 8; ++j) {
      const float4 xv = *(const float4*)&xs[rg * 8 + j][k4 * 4];  // wave-broadcast
      float s = fmaf(xv.x, wv.x, fmaf(xv.y, wv.y, fmaf(xv.z, wv.z, xv.w * wv.w)));
      acc[j] += s;
    }
  }
  #pragma unroll
  for (int j = 0; j < 8; ++j) {
    int node = node0 + rg * 8 + j;
    if (node < n_nodes) Y[(size_t)node * 64 + c] = acc[j];
  }
}

// ---------------- CSR build ----------------
__global__ __launch_bounds__(256) void hist_kernel(
    const int* __restrict__ ei, int* __restrict__ deg) {
  int e = blockIdx.x * 256 + threadIdx.x;
  if (e < NE) atomicAdd(&deg[ei[NE + e]], 1);
}

__global__ __launch_bounds__(256) void block_sum_kernel(
    const int* __restrict__ deg, int* __restrict__ bsums) {
  int idx = blockIdx.x * 256 + threadIdx.x;
  int v = (idx < NN) ? deg[idx] : 0;
  #pragma unroll
  for (int off = 32; off; off >>= 1) v += __shfl_down(v, off, 64);
  __shared__ int wsum[4];
  if ((threadIdx.x & 63) == 0) wsum[threadIdx.x >> 6] = v;
  __syncthreads();
  if (threadIdx.x == 0) bsums[blockIdx.x] = wsum[0] + wsum[1] + wsum[2] + wsum[3];
}

__global__ __launch_bounds__(256) void scan_bsums_kernel(
    const int* __restrict__ bsums, int* __restrict__ boffs) {
  int t = threadIdx.x;
  int v = (t < NB) ? bsums[t] : 0;
  __shared__ int ps[256];
  ps[t] = v;
  __syncthreads();
  for (int off = 1; off < 256; off <<= 1) {
    int add = (t >= off) ? ps[t - off] : 0;
    __syncthreads();
    ps[t] += add;
    __syncthreads();
  }
  boffs[t] = ps[t] - v;  // exclusive
}

__global__ __launch_bounds__(256) void scan_write_kernel(
    const int* __restrict__ deg, const int* __restrict__ boffs,
    int* __restrict__ rowptr, int* __restrict__ cursor) {
  int t = threadIdx.x;
  int idx = blockIdx.x * 256 + t;
  int v = (idx < NN) ? deg[idx] : 0;
  __shared__ int ps[256];
  ps[t] = v;
  __syncthreads();
  for (int off = 1; off < 256; off <<= 1) {
    int add = (t >= off) ? ps[t - off] : 0;
    __syncthreads();
    ps[t] += add;
    __syncthreads();
  }
  int ex = ps[t] - v + boffs[blockIdx.x];
  if (idx < NN) { rowptr[idx] = ex; cursor[idx] = ex; }
  if (idx == NN) rowptr[NN] = NE;
}

__global__ __launch_bounds__(256) void fill_kernel(
    const int* __restrict__ ei, int* __restrict__ cursor, int* __restrict__ srcs) {
  int e = blockIdx.x * 256 + threadIdx.x;
  if (e >= NE) return;
  int d = ei[NE + e];
  int pos = atomicAdd(&cursor[d], 1);
  srcs[pos] = ei[e];
}

// ---------------- gather-aggregate: 4 nodes/wave, float4/lane ----------------
__global__ __launch_bounds__(256) void gather4_kernel(
    const float* __restrict__ A, const int* __restrict__ rowptr,
    const int* __restrict__ srcs, float* __restrict__ B) {
  int lane = threadIdx.x & 63;
  int grp  = lane >> 4;    // 0..3: node within wave
  int sub  = lane & 15;    // float4 slot within row
  int wid  = (int)((blockIdx.x * 256u + (unsigned)threadIdx.x) >> 6);
  int node = wid * 4 + grp;
  if (node >= NN) return;
  int beg = rowptr[node], end = rowptr[node + 1];
  const float4* A4 = (const float4*)A;
  float4 a0 = make_float4(0.f, 0.f, 0.f, 0.f);
  float4 a1 = make_float4(0.f, 0.f, 0.f, 0.f);
  int i = beg;
  for (; i + 1 < end; i += 2) {
    int s0 = srcs[i], s1 = srcs[i + 1];
    float4 v0 = A4[(size_t)s0 * 16 + sub];
    float4 v1 = A4[(size_t)s1 * 16 + sub];
    a0.x += v0.x; a0.y += v0.y; a0.z += v0.z; a0.w += v0.w;
    a1.x += v1.x; a1.y += v1.y; a1.z += v1.z; a1.w += v1.w;
  }
  if (i < end) {
    float4 v = A4[(size_t)srcs[i] * 16 + sub];
    a0.x += v.x; a0.y += v.y; a0.z += v.z; a0.w += v.w;
  }
  float4 r = make_float4(a0.x + a1.x, a0.y + a1.y, a0.z + a1.z, a0.w + a1.w);
  ((float4*)B)[(size_t)node * 16 + sub] = r;
}

__device__ __forceinline__ int lb(const int* __restrict__ b, int n, int v) {
  int lo = 0, hi = n;
  while (lo < hi) { int mid = (lo + hi) >> 1; if (b[mid] < v) lo = mid + 1; else hi = mid; }
  return lo;
}

// ---------------- pool stage 1: grid-parallel partial sums ----------------
__global__ __launch_bounds__(256) void pool_partial_kernel(
    const float* __restrict__ h, const int* __restrict__ batch,
    const float* __restrict__ b2, float* __restrict__ sums) {
  int c = threadIdx.x & 63, w = threadIdx.x >> 6;
  int n0 = blockIdx.x * 128 + w * 32;
  float bias = b2[c];
  float acc = 0.f;
  int curg = -1;
  #pragma unroll 4
  for (int i = 0; i < 32; ++i) {
    int node = n0 + i;
    if (node >= NN) break;
    int g = batch[node];              // wave-uniform
    if (g != curg) {
      if (curg >= 0) atomicAdd(&sums[curg * 64 + c], acc);
      curg = g; acc = 0.f;
    }
    float v = h[(size_t)node * 64 + c] + bias;   // coalesced 256B/wave
    acc += v > 0.f ? v : 0.f;
  }
  if (curg >= 0) atomicAdd(&sums[curg * 64 + c], acc);
}

// ---------------- pool stage 2 + head ----------------
__global__ __launch_bounds__(64) void head_kernel(
    const float* __restrict__ sums, const int* __restrict__ batch,
    const float* __restrict__ fc1w, const float* __restrict__ fc1b,
    const float* __restrict__ fc2w, const float* __restrict__ fc2b,
    float* __restrict__ out) {
  int g = blockIdx.x;
  int t = threadIdx.x;
  __shared__ float pooled[64];
  __shared__ float z1[32];
  __shared__ float z2[10];
  int start = lb(batch, NN, g);
  int end   = lb(batch, NN, g + 1);
  float cnt = (float)(end - start);
  cnt = cnt > 1.f ? cnt : 1.f;
  pooled[t] = sums[g * 64 + t] / cnt;
  __syncthreads();
  if (t < 32) {
    float a = fc1b[t];
    #pragma unroll
    for (int k = 0; k < 64; ++k) a = fmaf(pooled[k], fc1w[k * 32 + t], a);
    z1[t] = a > 0.f ? a : 0.f;
  }
  __syncthreads();
  if (t < 10) {
    float a = fc2b[t];
    #pragma unroll
    for (int k = 0; k < 32; ++k) a = fmaf(z1[k], fc2w[k * 10 + t], a);
    z2[t] = a;
  }
  __syncthreads();
  if (t == 0) {
    float m = z2[0];
    for (int i = 1; i < 10; ++i) m = fmaxf(m, z2[i]);
    float s = 0.f;
    for (int i = 0; i < 10; ++i) s += expf(z2[i] - m);
    float lse = logf(s) + m;
    for (int i = 0; i < 10; ++i) out[g * 10 + i] = z2[i] - lse;
  }
}

extern "C" void kernel_launch(void* const* d_in, const int* in_sizes, int n_in,
                              void* d_out, int out_size, void* d_ws, size_t ws_size,
                              hipStream_t stream) {
  const float* x    = (const float*)d_in[0];
  const int*   ei   = (const int*)  d_in[1];   // [2, NE]
  const int*   bat  = (const int*)  d_in[2];
  const float* W1   = (const float*)d_in[3];
  const float* b1   = (const float*)d_in[4];
  const float* W2   = (const float*)d_in[5];
  const float* b2   = (const float*)d_in[6];
  const float* fc1w = (const float*)d_in[7];
  const float* fc1b = (const float*)d_in[8];
  const float* fc2w = (const float*)d_in[9];
  const float* fc2b = (const float*)d_in[10];
  float* out = (float*)d_out;

  char* ws = (char*)d_ws;
  float* A      = (float*)ws;                           // [NN,64]   12.8 MB
  float* B      = (float*)(ws + 12800000);              // [NN,64]   12.8 MB
  int*   rowptr = (int*)  (ws + 25600000);              // [NN+1]
  int*   cursor = (int*)  (ws + 25600000 + 4*(NN+1));   // [NN]
  int*   deg    = (int*)  (ws + 25600000 + 4*(2*NN+1)); // [NN]
  int*   srcs   = (int*)  (ws + 25600000 + 4*(3*NN+1)); // [NE]
  int*   bsums  = (int*)  (ws + 25600000 + 4*(3*NN+1) + 4*NE);        // [256]
  int*   boffs  = (int*)  (ws + 25600000 + 4*(3*NN+1) + 4*NE + 1024); // [256]
  float* sums   = (float*)(ws + 25600000 + 4*(3*NN+1) + 4*NE + 2048); // [NG,64]

  // ---- CSR build (counting sort by dst), shared by both layers ----
  hipMemsetAsync(deg, 0, NN * sizeof(int), stream);
  hist_kernel<<<(NE + 255) / 256, 256, 0, stream>>>(ei, deg);
  block_sum_kernel<<<NB, 256, 0, stream>>>(deg, bsums);
  scan_bsums_kernel<<<1, 256, 0, stream>>>(bsums, boffs);
  scan_write_kernel<<<NB, 256, 0, stream>>>(deg, boffs, rowptr, cursor);
  fill_kernel<<<(NE + 255) / 256, 256, 0, stream>>>(ei, cursor, srcs);

  // ---- layer 1: A = x@W1 ; B = gather(A) ----
  linear_kernel<128, false><<<(NN + 31) / 32, 256, 0, stream>>>(x, nullptr, W1, A, NN);
  gather4_kernel<<<3125, 256, 0, stream>>>(A, rowptr, srcs, B);

  // ---- layer 2: A = relu(B+b1)@W2 ; B = gather(A) ----
  linear_kernel<64, true><<<(NN + 31) / 32, 256, 0, stream>>>(B, b1, W2, A, NN);
  gather4_kernel<<<3125, 256, 0, stream>>>(A, rowptr, srcs, B);

  // ---- pool (partial sums) + head ----
  hipMemsetAsync(sums, 0, NG * 64 * sizeof(float), stream);
  pool_partial_kernel<<<(NN + 127) / 128, 256, 0, stream>>>(B, bat, b2, sums);
  head_kernel<<<NG, 64, 0, stream>>>(sums, bat, fc1w, fc1b, fc2w, fc2b, out);
}

// Round 7
// 244.768 us; speedup vs baseline: 3.6879x; 1.2999x over previous
//
#include <hip/hip_runtime.h>
#include <cstdint>
#include <cstddef>

#define NN 50000
#define NE 800000
#define NG 64
#define NBK 391          // ceil(NN/128) dst-buckets of 128 nodes
#define CAP 2816         // max edges/bucket staged in LDS (mean 2046, sd ~45)

typedef unsigned int uint;
typedef unsigned short ushort;

__device__ __forceinline__ ushort f2bf(float f) {   // RNE f32->bf16
  uint u = __float_as_uint(f);
  return (ushort)((u + 0x7FFFu + ((u >> 16) & 1u)) >> 16);
}
__device__ __forceinline__ float bf2f(ushort h) {
  return __uint_as_float(((uint)h) << 16);
}

// ---------------- Linear: Ybf16[n,64] = relu?(X + preb) @ W ----------------
// TIN = float or ushort(bf16). W staged transposed+padded (wsT row stride
// IN+4 dwords == 4 mod 32 banks -> conflict-free b128 per lane).
// launch_bounds(256,4): R5 showed VGPR=256 + 107MB spill writes when unbounded.
template<int IN, bool PREB, typename TIN>
__global__ __launch_bounds__(256, 4) void linear_kernel(
    const TIN* __restrict__ X, const float* __restrict__ preb,
    const float* __restrict__ W, ushort* __restrict__ Y, int n_nodes) {
  constexpr int NPB = 32;  // nodes per block
  __shared__ float xs[NPB][IN];
  __shared__ float wsT[64][IN + 4];
  const int tid = threadIdx.x;
  const int node0 = blockIdx.x * NPB;

  // stage W transposed (coalesced float4 reads; scalar LDS writes, once/block)
  for (int i = tid; i < IN * 16; i += 256) {
    float4 v = ((const float4*)W)[i];
    int k  = i >> 4;
    int c0 = (i & 15) << 2;
    wsT[c0 + 0][k] = v.x;
    wsT[c0 + 1][k] = v.y;
    wsT[c0 + 2][k] = v.z;
    wsT[c0 + 3][k] = v.w;
  }
  // stage X rows (zero-fill OOB tail), optional fused bias+relu
  const size_t gbase = (size_t)node0 * IN;
  const size_t gmax  = (size_t)n_nodes * IN;
  if constexpr (sizeof(TIN) == 4) {           // f32 input
    for (int i = tid; i < NPB * IN / 4; i += 256) {
      size_t g = gbase + (size_t)i * 4;
      float4 v = make_float4(0.f, 0.f, 0.f, 0.f);
      if (g + 3 < gmax) {
        v = ((const float4*)X)[g / 4];
        if (PREB) {
          float4 bv = ((const float4*)preb)[i & (IN / 4 - 1)];
          v.x = fmaxf(v.x + bv.x, 0.f);
          v.y = fmaxf(v.y + bv.y, 0.f);
          v.z = fmaxf(v.z + bv.z, 0.f);
          v.w = fmaxf(v.w + bv.w, 0.f);
        }
      }
      ((float4*)xs)[i] = v;
    }
  } else {                                    // bf16 input: 16B = 8 elems
    for (int i = tid; i < NPB * IN / 8; i += 256) {
      size_t g = gbase + (size_t)i * 8;
      float f[8];
      if (g + 7 < gmax) {
        uint4 u = ((const uint4*)X)[g / 8];
        f[0] = __uint_as_float(u.x << 16); f[1] = __uint_as_float(u.x & 0xFFFF0000u);
        f[2] = __uint_as_float(u.y << 16); f[3] = __uint_as_float(u.y & 0xFFFF0000u);
        f[4] = __uint_as_float(u.z << 16); f[5] = __uint_as_float(u.z & 0xFFFF0000u);
        f[6] = __uint_as_float(u.w << 16); f[7] = __uint_as_float(u.w & 0xFFFF0000u);
        if (PREB) {
          int c0 = (i * 8) & (IN - 1);
          #pragma unroll
          for (int j = 0; j < 8; ++j) f[j] = fmaxf(f[j] + preb[(c0 + j) & 63], 0.f);
        }
      } else {
        #pragma unroll
        for (int j = 0; j < 8; ++j) f[j] = 0.f;
      }
      #pragma unroll
      for (int j = 0; j < 8; ++j) (&xs[0][0])[i * 8 + j] = f[j];
    }
  }
  __syncthreads();

  const int c  = tid & 63;   // output channel (lane)
  const int rg = tid >> 6;   // wave id -> row group (8 nodes)
  float acc[8];
  #pragma unroll
  for (int j = 0; j < 8; ++j) acc[j] = 0.f;

  #pragma unroll 2
  for (int k4 = 0; k4 < IN / 4; ++k4) {
    const float4 wv = *(const float4*)&wsT[c][k4 * 4];   // 1 b128, conflict-free
    #pragma unroll
    for (int j = 0; j < 8; ++j) {
      const float4 xv = *(const float4*)&xs[rg * 8 + j][k4 * 4];  // wave-broadcast
      float s = fmaf(xv.x, wv.x, fmaf(xv.y, wv.y, fmaf(xv.z, wv.z, xv.w * wv.w)));
      acc[j] += s;
    }
  }
  #pragma unroll
  for (int j = 0; j < 8; ++j) {
    int node = node0 + rg * 8 + j;
    if (node < n_nodes) Y[(size_t)node * 64 + c] = f2bf(acc[j]);
  }
}

// ---------------- bucketed CSR build ----------------
// bucket b = dst >> 7 (128 nodes); pass A groups edges by bucket with
// LDS-aggregated claims (coalesced ~10-edge runs; R6 fill wrote 52MB via
// random 4B stores), pass B counting-sorts each bucket in LDS.

__global__ __launch_bounds__(256) void bhist_kernel(
    const int* __restrict__ ei, int* __restrict__ bcnt) {
  __shared__ int c[NBK];
  for (int i = threadIdx.x; i < NBK; i += 256) c[i] = 0;
  __syncthreads();
  for (int e = blockIdx.x * 256 + threadIdx.x; e < NE; e += NBK * 256)
    atomicAdd(&c[ei[NE + e] >> 7], 1);
  __syncthreads();
  for (int i = threadIdx.x; i < NBK; i += 256)
    if (c[i]) atomicAdd(&bcnt[i], c[i]);
}

__global__ __launch_bounds__(512) void bscan_kernel(
    const int* __restrict__ bcnt, int* __restrict__ bbase,
    int* __restrict__ bcur, int* __restrict__ rowptr) {
  int t = threadIdx.x;
  int v = (t < NBK) ? bcnt[t] : 0;
  __shared__ int ps[512];
  ps[t] = v;
  __syncthreads();
  for (int off = 1; off < 512; off <<= 1) {
    int add = (t >= off) ? ps[t - off] : 0;
    __syncthreads();
    ps[t] += add;
    __syncthreads();
  }
  if (t < NBK) { int ex = ps[t] - v; bbase[t] = ex; bcur[t] = ex; }
  if (t == 0) { bbase[NBK] = NE; rowptr[NN] = NE; }
}

// pass A: scatter edges into bucket-grouped ebuf, packed (src<<7)|(dst&127)
__global__ __launch_bounds__(256) void bscatter_kernel(
    const int* __restrict__ ei, int* __restrict__ bcur, uint* __restrict__ ebuf) {
  constexpr int EPT = 16;          // edges per thread; 4096/block
  __shared__ int cnt[NBK];
  __shared__ int gb[NBK];
  const int tid = threadIdx.x;
  for (int i = tid; i < NBK; i += 256) cnt[i] = 0;
  __syncthreads();
  const int e0 = blockIdx.x * (256 * EPT) + tid;
  uint val[EPT]; int off[EPT]; int bk[EPT];
  #pragma unroll
  for (int k = 0; k < EPT; ++k) {
    int e = e0 + k * 256;
    bk[k] = -1;
    if (e < NE) {
      int s = ei[e], d = ei[NE + e];
      bk[k]  = d >> 7;
      val[k] = ((uint)s << 7) | (uint)(d & 127);
      off[k] = atomicAdd(&cnt[bk[k]], 1);
    }
  }
  __syncthreads();
  for (int i = tid; i < NBK; i += 256)
    gb[i] = cnt[i] ? atomicAdd(&bcur[i], cnt[i]) : 0;
  __syncthreads();
  #pragma unroll
  for (int k = 0; k < EPT; ++k)
    if (bk[k] >= 0) ebuf[gb[bk[k]] + off[k]] = val[k];
}

// pass B: per-bucket counting sort in LDS -> srcs (coalesced) + rowptr
__global__ __launch_bounds__(256) void bsort_kernel(
    const uint* __restrict__ ebuf, const int* __restrict__ bbase,
    int* __restrict__ srcs, int* __restrict__ rowptr) {
  const int b = blockIdx.x;
  const int base = bbase[b];
  const int cnt  = bbase[b + 1] - base;
  const int tid = threadIdx.x;
  __shared__ int cntL[128], curL[128], ps[128];
  __shared__ int outL[CAP];
  if (tid < 128) cntL[tid] = 0;
  __syncthreads();
  for (int i = tid; i < cnt; i += 256)
    atomicAdd(&cntL[ebuf[base + i] & 127], 1);
  __syncthreads();
  int v = (tid < 128) ? cntL[tid] : 0;
  if (tid < 128) ps[tid] = v;
  __syncthreads();
  for (int off = 1; off < 128; off <<= 1) {
    int add = (tid < 128 && tid >= off) ? ps[tid - off] : 0;
    __syncthreads();
    if (tid < 128) ps[tid] += add;
    __syncthreads();
  }
  if (tid < 128) {
    int ex = ps[tid] - v;
    curL[tid] = ex;
    int node = b * 128 + tid;
    if (node < NN) rowptr[node] = base + ex;
  }
  __syncthreads();
  if (cnt <= CAP) {
    for (int i = tid; i < cnt; i += 256) {
      uint e = ebuf[base + i];
      int o = atomicAdd(&curL[e & 127], 1);
      outL[o] = (int)(e >> 7);
    }
    __syncthreads();
    for (int i = tid; i < cnt; i += 256) srcs[base + i] = outL[i];
  } else {  // safety fallback (never hit for this input distribution)
    for (int i = tid; i < cnt; i += 256) {
      uint e = ebuf[base + i];
      int o = atomicAdd(&curL[e & 127], 1);
      srcs[base + o] = (int)(e >> 7);
    }
  }
}

// ---------------- gather-aggregate: 4 nodes/wave, bf16 rows (128B) ----------------
template<bool OUT_BF16>
__global__ __launch_bounds__(256) void gather4_kernel(
    const ushort* __restrict__ A, const int* __restrict__ rowptr,
    const int* __restrict__ srcs, void* __restrict__ Bout) {
  int lane = threadIdx.x & 63;
  int grp  = lane >> 4;    // 0..3: node within wave
  int sub  = lane & 15;    // 4-channel slot within row
  int wid  = (int)((blockIdx.x * 256u + (unsigned)threadIdx.x) >> 6);
  int node = wid * 4 + grp;
  if (node >= NN) return;
  int beg = rowptr[node], end = rowptr[node + 1];
  const ushort4* A4 = (const ushort4*)A;   // 8B = 4 bf16 per lane
  float4 a0 = make_float4(0.f, 0.f, 0.f, 0.f);
  float4 a1 = make_float4(0.f, 0.f, 0.f, 0.f);
  int i = beg;
  for (; i + 1 < end; i += 2) {
    int s0 = srcs[i], s1 = srcs[i + 1];
    ushort4 u0 = A4[(size_t)s0 * 16 + sub];
    ushort4 u1 = A4[(size_t)s1 * 16 + sub];
    a0.x += bf2f(u0.x); a0.y += bf2f(u0.y); a0.z += bf2f(u0.z); a0.w += bf2f(u0.w);
    a1.x += bf2f(u1.x); a1.y += bf2f(u1.y); a1.z += bf2f(u1.z); a1.w += bf2f(u1.w);
  }
  if (i < end) {
    ushort4 u = A4[(size_t)srcs[i] * 16 + sub];
    a0.x += bf2f(u.x); a0.y += bf2f(u.y); a0.z += bf2f(u.z); a0.w += bf2f(u.w);
  }
  float4 r = make_float4(a0.x + a1.x, a0.y + a1.y, a0.z + a1.z, a0.w + a1.w);
  if (OUT_BF16) {
    ushort4 o; o.x = f2bf(r.x); o.y = f2bf(r.y); o.z = f2bf(r.z); o.w = f2bf(r.w);
    ((ushort4*)Bout)[(size_t)node * 16 + sub] = o;
  } else {
    ((float4*)Bout)[(size_t)node * 16 + sub] = r;
  }
}

__device__ __forceinline__ int lb(const int* __restrict__ b, int n, int v) {
  int lo = 0, hi = n;
  while (lo < hi) { int mid = (lo + hi) >> 1; if (b[mid] < v) lo = mid + 1; else hi = mid; }
  return lo;
}

// ---------------- pool stage 1: grid-parallel partial sums (f32 input) ----------------
__global__ __launch_bounds__(256) void pool_partial_kernel(
    const float* __restrict__ h, const int* __restrict__ batch,
    const float* __restrict__ b2, float* __restrict__ sums) {
  int c = threadIdx.x & 63, w = threadIdx.x >> 6;
  int n0 = blockIdx.x * 128 + w * 32;
  float bias = b2[c];
  float acc = 0.f;
  int curg = -1;
  #pragma unroll 4
  for (int i = 0; i < 32; ++i) {
    int node = n0 + i;
    if (node >= NN) break;
    int g = batch[node];              // wave-uniform
    if (g != curg) {
      if (curg >= 0) atomicAdd(&sums[curg * 64 + c], acc);
      curg = g; acc = 0.f;
    }
    float v = h[(size_t)node * 64 + c] + bias;   // coalesced 256B/wave
    acc += v > 0.f ? v : 0.f;
  }
  if (curg >= 0) atomicAdd(&sums[curg * 64 + c], acc);
}

// ---------------- pool stage 2 + head ----------------
__global__ __launch_bounds__(64) void head_kernel(
    const float* __restrict__ sums, const int* __restrict__ batch,
    const float* __restrict__ fc1w, const float* __restrict__ fc1b,
    const float* __restrict__ fc2w, const float* __restrict__ fc2b,
    float* __restrict__ out) {
  int g = blockIdx.x;
  int t = threadIdx.x;
  __shared__ float pooled[64];
  __shared__ float z1[32];
  __shared__ float z2[10];
  int start = lb(batch, NN, g);
  int end   = lb(batch, NN, g + 1);
  float cnt = (float)(end - start);
  cnt = cnt > 1.f ? cnt : 1.f;
  pooled[t] = sums[g * 64 + t] / cnt;
  __syncthreads();
  if (t < 32) {
    float a = fc1b[t];
    #pragma unroll
    for (int k = 0; k < 64; ++k) a = fmaf(pooled[k], fc1w[k * 32 + t], a);
    z1[t] = a > 0.f ? a : 0.f;
  }
  __syncthreads();
  if (t < 10) {
    float a = fc2b[t];
    #pragma unroll
    for (int k = 0; k < 32; ++k) a = fmaf(z1[k], fc2w[k * 10 + t], a);
    z2[t] = a;
  }
  __syncthreads();
  if (t == 0) {
    float m = z2[0];
    for (int i = 1; i < 10; ++i) m = fmaxf(m, z2[i]);
    float s = 0.f;
    for (int i = 0; i < 10; ++i) s += expf(z2[i] - m);
    float lse = logf(s) + m;
    for (int i = 0; i < 10; ++i) out[g * 10 + i] = z2[i] - lse;
  }
}

extern "C" void kernel_launch(void* const* d_in, const int* in_sizes, int n_in,
                              void* d_out, int out_size, void* d_ws, size_t ws_size,
                              hipStream_t stream) {
  const float* x    = (const float*)d_in[0];
  const int*   ei   = (const int*)  d_in[1];   // [2, NE]
  const int*   bat  = (const int*)  d_in[2];
  const float* W1   = (const float*)d_in[3];
  const float* b1   = (const float*)d_in[4];
  const float* W2   = (const float*)d_in[5];
  const float* b2   = (const float*)d_in[6];
  const float* fc1w = (const float*)d_in[7];
  const float* fc1b = (const float*)d_in[8];
  const float* fc2w = (const float*)d_in[9];
  const float* fc2b = (const float*)d_in[10];
  float* out = (float*)d_out;

  char* ws = (char*)d_ws;
  ushort* Abf   = (ushort*)ws;                    // [NN,64] bf16  6.4 MB
  ushort* B1bf  = (ushort*)(ws + 6400000);        // [NN,64] bf16  6.4 MB
  float*  B2    = (float*) (ws + 12800000);       // [NN,64] f32  12.8 MB
  uint*   ebuf  = (uint*)  (ws + 25600000);       // [NE]          3.2 MB
  int*    srcs  = (int*)   (ws + 28800000);       // [NE]          3.2 MB
  int*    rowptr= (int*)   (ws + 32000000);       // [NN+1]
  int*    bcnt  = (int*)   (ws + 32200016);       // [NBK]      } one memset
  float*  sums  = (float*) (ws + 32201584);       // [NG,64]    } (adjacent)
  int*    bbase = (int*)   (ws + 32217968);       // [NBK+1]
  int*    bcur  = (int*)   (ws + 32219552);       // [NBK]

  // ---- zero bcnt + sums in one memset (adjacent) ----
  hipMemsetAsync(bcnt, 0, 1568 + NG * 64 * sizeof(float), stream);

  // ---- bucketed CSR build (counting sort by dst), shared by both layers ----
  bhist_kernel<<<NBK, 256, 0, stream>>>(ei, bcnt);
  bscan_kernel<<<1, 512, 0, stream>>>(bcnt, bbase, bcur, rowptr);
  bscatter_kernel<<<(NE + 4095) / 4096, 256, 0, stream>>>(ei, bcur, ebuf);
  bsort_kernel<<<NBK, 256, 0, stream>>>(ebuf, bbase, srcs, rowptr);

  // ---- layer 1: Abf = bf16(x@W1) ; B1bf = bf16(gather(Abf)) ----
  linear_kernel<128, false, float><<<(NN + 31) / 32, 256, 0, stream>>>(x, nullptr, W1, Abf, NN);
  gather4_kernel<true><<<3125, 256, 0, stream>>>(Abf, rowptr, srcs, B1bf);

  // ---- layer 2: Abf = bf16(relu(B1bf+b1)@W2) ; B2 = gather(Abf) f32 ----
  linear_kernel<64, true, ushort><<<(NN + 31) / 32, 256, 0, stream>>>(B1bf, b1, W2, Abf, NN);
  gather4_kernel<false><<<3125, 256, 0, stream>>>(Abf, rowptr, srcs, B2);

  // ---- pool (partial sums) + head ----
  pool_partial_kernel<<<(NN + 127) / 128, 256, 0, stream>>>(B2, bat, b2, sums);
  head_kernel<<<NG, 64, 0, stream>>>(sums, bat, fc1w, fc1b, fc2w, fc2b, out);
}

// Round 8
// 225.376 us; speedup vs baseline: 4.0052x; 1.0860x over previous
//
#include <hip/hip_runtime.h>
#include <cstdint>
#include <cstddef>

#define NN 50000
#define NE 800000
#define NG 64
#define NBK 391          // ceil(NN/128) dst-buckets of 128 nodes
#define CAP 2816         // max edges/bucket staged in LDS (mean 2046, sd ~45)

typedef unsigned int uint;
typedef unsigned short ushort;
typedef __attribute__((ext_vector_type(8))) short bf16x8;
typedef __attribute__((ext_vector_type(4))) float f32x4;

__device__ __forceinline__ ushort f2bf(float f) {   // RNE f32->bf16
  uint u = __float_as_uint(f);
  return (ushort)((u + 0x7FFFu + ((u >> 16) & 1u)) >> 16);
}
__device__ __forceinline__ float bf2f(ushort h) {
  return __uint_as_float(((uint)h) << 16);
}
__device__ __forceinline__ uint pk(float a, float b) {
  return (uint)f2bf(a) | ((uint)f2bf(b) << 16);
}

// ---------------- W^T prep (once): wt_g[c][k] = bf16(W[k][c]) ----------------
__global__ __launch_bounds__(256) void wprep_kernel(
    const float* __restrict__ W1, const float* __restrict__ W2,
    ushort* __restrict__ wt1, ushort* __restrict__ wt2) {
  if (blockIdx.x == 0) {
    for (int i = threadIdx.x; i < 128 * 64; i += 256) {
      int k = i >> 6, c = i & 63;
      wt1[c * 128 + k] = f2bf(W1[i]);
    }
  } else {
    for (int i = threadIdx.x; i < 64 * 64; i += 256) {
      int k = i >> 6, c = i & 63;
      wt2[c * 64 + k] = f2bf(W2[i]);
    }
  }
}

// ---------------- MFMA linear: Ybf16[n,64] = relu?(X + preb) @ W ----------------
// 4 waves/block, 64 nodes/block, wave = 16 nodes x 64 out.
// mfma_f32_16x16x32_bf16: A lane: row=l&15, k=8*(l>>4)+j; B lane: col=l&15, same k;
// D: col=l&15, row=4*(l>>4)+reg  [learn_hip m89].
// LDS rows padded to IN+8 bf16 -> b128 frag reads spread over all 8 bank slots.
template<int IN, bool PREB>
__global__ __launch_bounds__(256, 4) void linear_mfma_kernel(
    const void* __restrict__ Xv, const float* __restrict__ preb,
    const ushort* __restrict__ wt_g, ushort* __restrict__ Y, int n_nodes) {
  constexpr int NPB = 64;
  constexpr int LDK = IN + 8;
  __shared__ ushort xs[NPB][LDK];
  __shared__ ushort wt[64][LDK];
  const int tid = threadIdx.x;
  const int node0 = blockIdx.x * NPB;

  // stage W^T (coalesced uint4 row copies; row offset LDK*2 is 16B-aligned)
  for (int i = tid; i < 64 * IN / 8; i += 256) {
    int rr = i / (IN / 8), k0 = (i % (IN / 8)) * 8;
    *(uint4*)&wt[rr][k0] = ((const uint4*)wt_g)[i];
  }
  // stage X rows as bf16 (zero-fill OOB), optional fused bias+relu
  if constexpr (!PREB) {                       // f32 input (layer 1)
    const float* X = (const float*)Xv;
    for (int i = tid; i < NPB * IN / 4; i += 256) {
      int r = i / (IN / 4), k0 = (i % (IN / 4)) * 4;
      int node = node0 + r;
      float4 v = make_float4(0.f, 0.f, 0.f, 0.f);
      if (node < n_nodes) v = ((const float4*)X)[(size_t)node * (IN / 4) + (k0 >> 2)];
      *(uint2*)&xs[r][k0] = make_uint2(pk(v.x, v.y), pk(v.z, v.w));
    }
  } else {                                     // bf16 input + bias + relu (layer 2)
    const ushort* X = (const ushort*)Xv;
    for (int i = tid; i < NPB * IN / 8; i += 256) {
      int r = i / (IN / 8), k0 = (i % (IN / 8)) * 8;
      int node = node0 + r;
      float f[8];
      if (node < n_nodes) {
        uint4 u = ((const uint4*)X)[(size_t)node * (IN / 8) + (k0 >> 3)];
        f[0] = __uint_as_float(u.x << 16); f[1] = __uint_as_float(u.x & 0xFFFF0000u);
        f[2] = __uint_as_float(u.y << 16); f[3] = __uint_as_float(u.y & 0xFFFF0000u);
        f[4] = __uint_as_float(u.z << 16); f[5] = __uint_as_float(u.z & 0xFFFF0000u);
        f[6] = __uint_as_float(u.w << 16); f[7] = __uint_as_float(u.w & 0xFFFF0000u);
        #pragma unroll
        for (int j = 0; j < 8; ++j) f[j] = fmaxf(f[j] + preb[k0 + j], 0.f);
      } else {
        #pragma unroll
        for (int j = 0; j < 8; ++j) f[j] = 0.f;
      }
      uint4 o;
      o.x = pk(f[0], f[1]); o.y = pk(f[2], f[3]);
      o.z = pk(f[4], f[5]); o.w = pk(f[6], f[7]);
      *(uint4*)&xs[r][k0] = o;
    }
  }
  __syncthreads();

  const int lane = tid & 63, wid = tid >> 6;
  const int r = lane & 15, q = lane >> 4;
  const int arow = wid * 16 + r;
  f32x4 acc[4];
  #pragma unroll
  for (int nt = 0; nt < 4; ++nt) acc[nt] = (f32x4){0.f, 0.f, 0.f, 0.f};

  #pragma unroll
  for (int ks = 0; ks < IN / 32; ++ks) {
    const bf16x8 a = *(const bf16x8*)&xs[arow][ks * 32 + q * 8];
    #pragma unroll
    for (int nt = 0; nt < 4; ++nt) {
      const bf16x8 b = *(const bf16x8*)&wt[nt * 16 + r][ks * 32 + q * 8];
      acc[nt] = __builtin_amdgcn_mfma_f32_16x16x32_bf16(a, b, acc[nt], 0, 0, 0);
    }
  }
  // D: row (node) = 4*q + i, col = nt*16 + r
  #pragma unroll
  for (int nt = 0; nt < 4; ++nt) {
    #pragma unroll
    for (int i = 0; i < 4; ++i) {
      int node = node0 + wid * 16 + q * 4 + i;
      if (node < n_nodes) Y[(size_t)node * 64 + nt * 16 + r] = f2bf(acc[nt][i]);
    }
  }
}

// ---------------- bucketed CSR build (unchanged from R7) ----------------
__global__ __launch_bounds__(256) void bhist_kernel(
    const int* __restrict__ ei, int* __restrict__ bcnt) {
  __shared__ int c[NBK];
  for (int i = threadIdx.x; i < NBK; i += 256) c[i] = 0;
  __syncthreads();
  for (int e = blockIdx.x * 256 + threadIdx.x; e < NE; e += NBK * 256)
    atomicAdd(&c[ei[NE + e] >> 7], 1);
  __syncthreads();
  for (int i = threadIdx.x; i < NBK; i += 256)
    if (c[i]) atomicAdd(&bcnt[i], c[i]);
}

__global__ __launch_bounds__(512) void bscan_kernel(
    const int* __restrict__ bcnt, int* __restrict__ bbase,
    int* __restrict__ bcur, int* __restrict__ rowptr) {
  int t = threadIdx.x;
  int v = (t < NBK) ? bcnt[t] : 0;
  __shared__ int ps[512];
  ps[t] = v;
  __syncthreads();
  for (int off = 1; off < 512; off <<= 1) {
    int add = (t >= off) ? ps[t - off] : 0;
    __syncthreads();
    ps[t] += add;
    __syncthreads();
  }
  if (t < NBK) { int ex = ps[t] - v; bbase[t] = ex; bcur[t] = ex; }
  if (t == 0) { bbase[NBK] = NE; rowptr[NN] = NE; }
}

__global__ __launch_bounds__(256) void bscatter_kernel(
    const int* __restrict__ ei, int* __restrict__ bcur, uint* __restrict__ ebuf) {
  constexpr int EPT = 16;          // edges per thread; 4096/block
  __shared__ int cnt[NBK];
  __shared__ int gb[NBK];
  const int tid = threadIdx.x;
  for (int i = tid; i < NBK; i += 256) cnt[i] = 0;
  __syncthreads();
  const int e0 = blockIdx.x * (256 * EPT) + tid;
  uint val[EPT]; int off[EPT]; int bk[EPT];
  #pragma unroll
  for (int k = 0; k < EPT; ++k) {
    int e = e0 + k * 256;
    bk[k] = -1;
    if (e < NE) {
      int s = ei[e], d = ei[NE + e];
      bk[k]  = d >> 7;
      val[k] = ((uint)s << 7) | (uint)(d & 127);
      off[k] = atomicAdd(&cnt[bk[k]], 1);
    }
  }
  __syncthreads();
  for (int i = tid; i < NBK; i += 256)
    gb[i] = cnt[i] ? atomicAdd(&bcur[i], cnt[i]) : 0;
  __syncthreads();
  #pragma unroll
  for (int k = 0; k < EPT; ++k)
    if (bk[k] >= 0) ebuf[gb[bk[k]] + off[k]] = val[k];
}

__global__ __launch_bounds__(256) void bsort_kernel(
    const uint* __restrict__ ebuf, const int* __restrict__ bbase,
    int* __restrict__ srcs, int* __restrict__ rowptr) {
  const int b = blockIdx.x;
  const int base = bbase[b];
  const int cnt  = bbase[b + 1] - base;
  const int tid = threadIdx.x;
  __shared__ int cntL[128], curL[128], ps[128];
  __shared__ int outL[CAP];
  if (tid < 128) cntL[tid] = 0;
  __syncthreads();
  for (int i = tid; i < cnt; i += 256)
    atomicAdd(&cntL[ebuf[base + i] & 127], 1);
  __syncthreads();
  int v = (tid < 128) ? cntL[tid] : 0;
  if (tid < 128) ps[tid] = v;
  __syncthreads();
  for (int off = 1; off < 128; off <<= 1) {
    int add = (tid < 128 && tid >= off) ? ps[tid - off] : 0;
    __syncthreads();
    if (tid < 128) ps[tid] += add;
    __syncthreads();
  }
  if (tid < 128) {
    int ex = ps[tid] - v;
    curL[tid] = ex;
    int node = b * 128 + tid;
    if (node < NN) rowptr[node] = base + ex;
  }
  __syncthreads();
  if (cnt <= CAP) {
    for (int i = tid; i < cnt; i += 256) {
      uint e = ebuf[base + i];
      int o = atomicAdd(&curL[e & 127], 1);
      outL[o] = (int)(e >> 7);
    }
    __syncthreads();
    for (int i = tid; i < cnt; i += 256) srcs[base + i] = outL[i];
  } else {  // safety fallback
    for (int i = tid; i < cnt; i += 256) {
      uint e = ebuf[base + i];
      int o = atomicAdd(&curL[e & 127], 1);
      srcs[base + o] = (int)(e >> 7);
    }
  }
}

// ---------------- gather-aggregate: 4 nodes/wave, bf16 in/out (128B rows) ----------------
__global__ __launch_bounds__(256) void gather4_kernel(
    const ushort* __restrict__ A, const int* __restrict__ rowptr,
    const int* __restrict__ srcs, ushort* __restrict__ B) {
  int lane = threadIdx.x & 63;
  int grp  = lane >> 4;    // 0..3: node within wave
  int sub  = lane & 15;    // 4-channel slot within row
  int wid  = (int)((blockIdx.x * 256u + (unsigned)threadIdx.x) >> 6);
  int node = wid * 4 + grp;
  if (node >= NN) return;
  int beg = rowptr[node], end = rowptr[node + 1];
  const ushort4* A4 = (const ushort4*)A;   // 8B = 4 bf16 per lane
  float4 a0 = make_float4(0.f, 0.f, 0.f, 0.f);
  float4 a1 = make_float4(0.f, 0.f, 0.f, 0.f);
  int i = beg;
  for (; i + 1 < end; i += 2) {
    int s0 = srcs[i], s1 = srcs[i + 1];
    ushort4 u0 = A4[(size_t)s0 * 16 + sub];
    ushort4 u1 = A4[(size_t)s1 * 16 + sub];
    a0.x += bf2f(u0.x); a0.y += bf2f(u0.y); a0.z += bf2f(u0.z); a0.w += bf2f(u0.w);
    a1.x += bf2f(u1.x); a1.y += bf2f(u1.y); a1.z += bf2f(u1.z); a1.w += bf2f(u1.w);
  }
  if (i < end) {
    ushort4 u = A4[(size_t)srcs[i] * 16 + sub];
    a0.x += bf2f(u.x); a0.y += bf2f(u.y); a0.z += bf2f(u.z); a0.w += bf2f(u.w);
  }
  ushort4 o;
  o.x = f2bf(a0.x + a1.x); o.y = f2bf(a0.y + a1.y);
  o.z = f2bf(a0.z + a1.z); o.w = f2bf(a0.w + a1.w);
  ((ushort4*)B)[(size_t)node * 16 + sub] = o;
}

__device__ __forceinline__ int lb(const int* __restrict__ b, int n, int v) {
  int lo = 0, hi = n;
  while (lo < hi) { int mid = (lo + hi) >> 1; if (b[mid] < v) lo = mid + 1; else hi = mid; }
  return lo;
}

// ---------------- pool stage 1: grid-parallel partial sums (bf16 input) ----------------
__global__ __launch_bounds__(256) void pool_partial_kernel(
    const ushort* __restrict__ h, const int* __restrict__ batch,
    const float* __restrict__ b2, float* __restrict__ sums) {
  int c = threadIdx.x & 63, w = threadIdx.x >> 6;
  int n0 = blockIdx.x * 128 + w * 32;
  float bias = b2[c];
  float acc = 0.f;
  int curg = -1;
  #pragma unroll 4
  for (int i = 0; i < 32; ++i) {
    int node = n0 + i;
    if (node >= NN) break;
    int g = batch[node];              // wave-uniform
    if (g != curg) {
      if (curg >= 0) atomicAdd(&sums[curg * 64 + c], acc);
      curg = g; acc = 0.f;
    }
    float v = bf2f(h[(size_t)node * 64 + c]) + bias;   // coalesced 128B/wave
    acc += v > 0.f ? v : 0.f;
  }
  if (curg >= 0) atomicAdd(&sums[curg * 64 + c], acc);
}

// ---------------- pool stage 2 + head ----------------
__global__ __launch_bounds__(64) void head_kernel(
    const float* __restrict__ sums, const int* __restrict__ batch,
    const float* __restrict__ fc1w, const float* __restrict__ fc1b,
    const float* __restrict__ fc2w, const float* __restrict__ fc2b,
    float* __restrict__ out) {
  int g = blockIdx.x;
  int t = threadIdx.x;
  __shared__ float pooled[64];
  __shared__ float z1[32];
  __shared__ float z2[10];
  int start = lb(batch, NN, g);
  int end   = lb(batch, NN, g + 1);
  float cnt = (float)(end - start);
  cnt = cnt > 1.f ? cnt : 1.f;
  pooled[t] = sums[g * 64 + t] / cnt;
  __syncthreads();
  if (t < 32) {
    float a = fc1b[t];
    #pragma unroll
    for (int k = 0; k < 64; ++k) a = fmaf(pooled[k], fc1w[k * 32 + t], a);
    z1[t] = a > 0.f ? a : 0.f;
  }
  __syncthreads();
  if (t < 10) {
    float a = fc2b[t];
    #pragma unroll
    for (int k = 0; k < 32; ++k) a = fmaf(z1[k], fc2w[k * 10 + t], a);
    z2[t] = a;
  }
  __syncthreads();
  if (t == 0) {
    float m = z2[0];
    for (int i = 1; i < 10; ++i) m = fmaxf(m, z2[i]);
    float s = 0.f;
    for (int i = 0; i < 10; ++i) s += expf(z2[i] - m);
    float lse = logf(s) + m;
    for (int i = 0; i < 10; ++i) out[g * 10 + i] = z2[i] - lse;
  }
}

extern "C" void kernel_launch(void* const* d_in, const int* in_sizes, int n_in,
                              void* d_out, int out_size, void* d_ws, size_t ws_size,
                              hipStream_t stream) {
  const float* x    = (const float*)d_in[0];
  const int*   ei   = (const int*)  d_in[1];   // [2, NE]
  const int*   bat  = (const int*)  d_in[2];
  const float* W1   = (const float*)d_in[3];
  const float* b1   = (const float*)d_in[4];
  const float* W2   = (const float*)d_in[5];
  const float* b2   = (const float*)d_in[6];
  const float* fc1w = (const float*)d_in[7];
  const float* fc1b = (const float*)d_in[8];
  const float* fc2w = (const float*)d_in[9];
  const float* fc2b = (const float*)d_in[10];
  float* out = (float*)d_out;

  char* ws = (char*)d_ws;
  ushort* Abf   = (ushort*)ws;                    // [NN,64] bf16  6.4 MB
  ushort* B1bf  = (ushort*)(ws + 6400000);        // [NN,64] bf16  6.4 MB
  ushort* B2bf  = (ushort*)(ws + 12800000);       // [NN,64] bf16  6.4 MB
  ushort* wt1g  = (ushort*)(ws + 19200000);       // [64,128] bf16 16 KB
  ushort* wt2g  = (ushort*)(ws + 19216384);       // [64,64] bf16   8 KB
  uint*   ebuf  = (uint*)  (ws + 25600000);       // [NE]          3.2 MB
  int*    srcs  = (int*)   (ws + 28800000);       // [NE]          3.2 MB
  int*    rowptr= (int*)   (ws + 32000000);       // [NN+1]
  int*    bcnt  = (int*)   (ws + 32200016);       // [NBK]      } one memset
  float*  sums  = (float*) (ws + 32201584);       // [NG,64]    } (adjacent)
  int*    bbase = (int*)   (ws + 32217968);       // [NBK+1]
  int*    bcur  = (int*)   (ws + 32219552);       // [NBK]

  // ---- zero bcnt + sums in one memset (adjacent) ----
  hipMemsetAsync(bcnt, 0, 1568 + NG * 64 * sizeof(float), stream);

  // ---- W^T bf16 prep (shared by all blocks of both linears) ----
  wprep_kernel<<<2, 256, 0, stream>>>(W1, W2, wt1g, wt2g);

  // ---- bucketed CSR build (counting sort by dst), shared by both layers ----
  bhist_kernel<<<NBK, 256, 0, stream>>>(ei, bcnt);
  bscan_kernel<<<1, 512, 0, stream>>>(bcnt, bbase, bcur, rowptr);
  bscatter_kernel<<<(NE + 4095) / 4096, 256, 0, stream>>>(ei, bcur, ebuf);
  bsort_kernel<<<NBK, 256, 0, stream>>>(ebuf, bbase, srcs, rowptr);

  // ---- layer 1: Abf = bf16(x@W1) ; B1bf = bf16(gather(Abf)) ----
  linear_mfma_kernel<128, false><<<(NN + 63) / 64, 256, 0, stream>>>(x, nullptr, wt1g, Abf, NN);
  gather4_kernel<<<3125, 256, 0, stream>>>(Abf, rowptr, srcs, B1bf);

  // ---- layer 2: Abf = bf16(relu(B1bf+b1)@W2) ; B2bf = bf16(gather(Abf)) ----
  linear_mfma_kernel<64, true><<<(NN + 63) / 64, 256, 0, stream>>>(B1bf, b1, wt2g, Abf, NN);
  gather4_kernel<<<3125, 256, 0, stream>>>(Abf, rowptr, srcs, B2bf);

  // ---- pool (partial sums) + head ----
  pool_partial_kernel<<<(NN + 127) / 128, 256, 0, stream>>>(B2bf, bat, b2, sums);
  head_kernel<<<NG, 64, 0, stream>>>(sums, bat, fc1w, fc1b, fc2w, fc2b, out);
}